// Round 10
// baseline (489.714 us; speedup 1.0000x reference)
//
#include <hip/hip_runtime.h>
#include <hip/hip_bf16.h>

using bf16 = __hip_bfloat16;
typedef short bf16x8 __attribute__((ext_vector_type(8)));
typedef float f32x4 __attribute__((ext_vector_type(4)));

#define AS1 __attribute__((address_space(1)))
#define AS3 __attribute__((address_space(3)))

__device__ inline float b2f(bf16 h) { return __bfloat162float(h); }
__device__ inline bf16 f2b(float f) { return __float2bfloat16(f); }
__device__ inline unsigned short f2bu(float f) {
    bf16 h = __float2bfloat16(f);
    unsigned short u;
    __builtin_memcpy(&u, &h, 2);
    return u;
}
__device__ inline float su2f(unsigned short u) {
    unsigned v = ((unsigned)u) << 16;
    return __uint_as_float(v);
}
// async global->LDS, 16B per lane, LDS dest = wave-uniform base + lane*16
__device__ inline void gload16(const bf16* gp, short* lp) {
    __builtin_amdgcn_global_load_lds((const AS1 void*)gp, (AS3 void*)lp, 16, 0, 0);
}
__device__ inline float fast_rcp(float a) {
#if __has_builtin(__builtin_amdgcn_rcpf)
    return __builtin_amdgcn_rcpf(a);   // v_rcp_f32, 1 instr, ~1ulp
#else
    return 1.0f / a;                   // fallback: IEEE divide
#endif
}
// NewGELU. 0.5*x*(1+tanh(z)) == x * sigmoid(2z) = x * rcp(1 + exp2(-c2*(x+a*x^3)))
// c2 = 2*sqrt(2/pi)*log2(e). HW v_exp_f32 IS exp2 -> no ln2 premul. ~8 VALU ops
// vs ~16 for the IEEE-divide form (v_div_scale/rcp/div_fmas/div_fixup chain).
__device__ inline float gelu_new(float x) {
    float x3 = x * x * x;
    float z = -2.3022082f * __builtin_fmaf(0.044715f, x3, x);
    float e = exp2f(z);                // single v_exp_f32
    return x * fast_rcp(1.0f + e);     // exact limits: e->inf => 0
}

// ---------------- zero page (halo source for global_load_lds) ----------------
__global__ __launch_bounds__(64) void zero_page(float* z) { z[threadIdx.x] = 0.f; }

// ---------------- weight pack: [O][I][3][3] f32 -> [tap][CO_TOTAL][CI] bf16 --
__global__ __launch_bounds__(256) void pack_w(const float* __restrict__ w,
                                              bf16* __restrict__ wpk,
                                              int CO, int CI, int CO_TOTAL, int co_off) {
    int i = blockIdx.x * 256 + threadIdx.x;
    int total = CO * CI * 9;
    if (i < total) {
        int tap = i % 9;
        int ci = (i / 9) % CI;
        int co = i / (9 * CI);
        wpk[((size_t)tap * CO_TOTAL + co_off + co) * CI + ci] = f2b(w[i]);
    }
}

// ---------------- g/b transpose NCHW f32 -> NHWC f32 ----------
__global__ __launch_bounds__(256) void gtrans_k(const float* __restrict__ g,
                                                const float* __restrict__ bb,
                                                float* __restrict__ gt,
                                                float* __restrict__ bt) {
    int i = blockIdx.x * 256 + threadIdx.x;
    int sel = i >> 17;
    int o = i & 131071;
    int p = o >> 5, c = o & 31;
    int src = c * 4096 + p;
    if (sel == 0) gt[o] = g[src];
    else          bt[o] = bb[src];
}

// ---------------- LN partial reduce: grid (8, 128) ----------------
template <typename TIN>
__global__ __launch_bounds__(256) void ln_part(const void* __restrict__ xin,
                                               float2* __restrict__ spart) {
    const int tid = threadIdx.x;
    const int sample = blockIdx.y, seg = blockIdx.x;
    const size_t base = (size_t)sample * 131072 + seg * 16384;
    float sum = 0.f, ss = 0.f;
    if constexpr (sizeof(TIN) == 4) {
        const float4* p = (const float4*)((const float*)xin + base);
        for (int l = 0; l < 16; ++l) {
            float4 v = p[l * 256 + tid];
            sum += v.x + v.y + v.z + v.w;
            ss += v.x * v.x + v.y * v.y + v.z * v.z + v.w * v.w;
        }
    } else {
        const uint4* p = (const uint4*)((const bf16*)xin + base);
        for (int l = 0; l < 8; ++l) {
            uint4 u = p[l * 256 + tid];
            unsigned w[4] = {u.x, u.y, u.z, u.w};
#pragma unroll
            for (int j = 0; j < 4; ++j) {
                float lo = __uint_as_float(w[j] << 16);
                float hi = __uint_as_float(w[j] & 0xffff0000u);
                sum += lo + hi;
                ss += lo * lo + hi * hi;
            }
        }
    }
    __shared__ float rs[256], rs2[256];
    rs[tid] = sum; rs2[tid] = ss;
    __syncthreads();
    for (int off = 128; off > 0; off >>= 1) {
        if (tid < off) { rs[tid] += rs[tid + off]; rs2[tid] += rs2[tid + off]; }
        __syncthreads();
    }
    if (tid == 0) spart[sample * 8 + seg] = make_float2(rs[0], rs2[0]);
}

// ---------------- LN finalize ----------------
__global__ __launch_bounds__(128) void ln_fin(const float2* __restrict__ spart,
                                              float2* __restrict__ stats) {
    int t = threadIdx.x;
    float s = 0.f, ss = 0.f;
    for (int j = 0; j < 8; ++j) {
        float2 v = spart[t * 8 + j];
        s += v.x; ss += v.y;
    }
    float m = s / 131072.f;
    float var = ss / 131072.f - m * m;
    stats[t] = make_float2(m, rsqrtf(var + 1e-5f));
}

// ---------------- LN1 normalize + NCHW->NHWC transpose ----------------
__global__ __launch_bounds__(256) void ln1_norm_t(const float* __restrict__ x,
                                                  const float* __restrict__ g,
                                                  const float* __restrict__ bb,
                                                  const float2* __restrict__ stats,
                                                  bf16* __restrict__ out) {
    __shared__ float tile[32][129];
    const int tid = threadIdx.x;
    const int sample = blockIdx.y;
    const int p0 = blockIdx.x * 128;
    float2 st = stats[sample];
    const float m = st.x, r = st.y;
    const size_t xb = (size_t)sample * 131072;
    for (int k = 0; k < 16; ++k) {
        int idx = k * 256 + tid;
        int c = idx >> 7, p = idx & 127;
        int gi = c * 4096 + p0 + p;
        float v = x[xb + gi];
        tile[c][p] = (v - m) * r * g[gi] + bb[gi];
    }
    __syncthreads();
    for (int k = 0; k < 8; ++k) {
        int idx = k * 256 + tid;
        int p = idx >> 4, c2 = (idx & 15) * 2;
        unsigned lo = (unsigned)f2bu(tile[c2][p]);
        unsigned hi = (unsigned)f2bu(tile[c2 + 1][p]);
        *(unsigned*)&out[xb + (size_t)(p0 + p) * 32 + c2] = lo | (hi << 16);
    }
}

// ---------------- LN2 normalize, NHWC linear ----------------
__global__ __launch_bounds__(256) void ln2_norm(const bf16* __restrict__ xin,
                                                const float* __restrict__ gt,
                                                const float* __restrict__ bt,
                                                const float2* __restrict__ stats,
                                                bf16* __restrict__ out) {
    const int tid = threadIdx.x;
    const int sample = blockIdx.y;
    float2 st = stats[sample];
    const float m = st.x, r = st.y;
    int i0 = (blockIdx.x * 256 + tid) * 8;
    const size_t base = (size_t)sample * 131072 + i0;
    uint4 u = *(const uint4*)&xin[base];
    float4 g0 = *(const float4*)&gt[i0];
    float4 g1 = *(const float4*)&gt[i0 + 4];
    float4 b0 = *(const float4*)&bt[i0];
    float4 b1 = *(const float4*)&bt[i0 + 4];
    unsigned w[4] = {u.x, u.y, u.z, u.w};
    float gv[8] = {g0.x, g0.y, g0.z, g0.w, g1.x, g1.y, g1.z, g1.w};
    float bv[8] = {b0.x, b0.y, b0.z, b0.w, b1.x, b1.y, b1.z, b1.w};
    unsigned o[4];
#pragma unroll
    for (int j = 0; j < 4; ++j) {
        float lo = __uint_as_float(w[j] << 16);
        float hi = __uint_as_float(w[j] & 0xffff0000u);
        lo = (lo - m) * r * gv[2 * j] + bv[2 * j];
        hi = (hi - m) * r * gv[2 * j + 1] + bv[2 * j + 1];
        o[j] = (unsigned)f2bu(lo) | ((unsigned)f2bu(hi) << 16);
    }
    uint4 st4 = make_uint4(o[0], o[1], o[2], o[3]);
    *(uint4*)&out[base] = st4;
}

// ---------------- stride-1 conv: async global_load_lds staging --------------
// LDS is item-linear (global_load_lds writes wave-uniform base + lane*16);
// the bank swizzle is applied on the GLOBAL source address (XOR involution
// grp = sub ^ f(x)), so LDS contents match the read-side swizzle exactly.
// Halo lanes load from a zero page.
template <int CI, int CO_TOTAL, int CO_BLK, int EPI, int ROWS = 4>
__global__ __launch_bounds__(ROWS * 64) void conv_lds(const bf16* __restrict__ in,
                                                      const bf16* __restrict__ wpk,
                                                      const float* __restrict__ bias,
                                                      const void* __restrict__ res,
                                                      void* __restrict__ out,
                                                      const bf16* __restrict__ zpage,
                                                      int in_s0, int out_s0) {
    constexpr int CHUNKS = CI / 32;
    constexpr int MT = CO_BLK / 16;
    constexpr int NG = 64 / ROWS;
    constexpr int NT = ROWS * 64;
    constexpr int HR = ROWS + 2;
    constexpr int IN_ITEMS = HR * 66 * 4;                 // 16B items
    constexpr int IN_PAD = ((IN_ITEMS + 63) / 64) * 64;   // wave-group padded
    constexpr int IN_ITERS = (IN_PAD + NT - 1) / NT;
    constexpr int W_ITEMS = 9 * CO_BLK * 4;               // always %64 == 0
    constexpr int W_ITERS = (W_ITEMS + NT - 1) / NT;

    __shared__ short s_in[IN_PAD * 8];
    __shared__ short s_w[9 * CO_BLK * 32];

    const int tid = threadIdx.x;
    const int lane = tid & 63;
    const int wv = tid >> 6;
    const int quad = lane >> 4;
    const int n16 = lane & 15;

    const int ng = blockIdx.x % NG;
    const int cg = blockIdx.x / NG;
    const int co0 = cg * CO_BLK;
    const int smp = blockIdx.y;
    const int y0 = ng * ROWS;

    const size_t in_base = (size_t)(in_s0 + smp) * 4096 * CI;

    // chunk-invariant staging geometry (source pre-swizzled, -1 => zero page)
    int gin[IN_ITERS];
#pragma unroll
    for (int it = 0; it < IN_ITERS; ++it) {
        int i = it * NT + tid;
        int sub = i & 3;
        int x = (i >> 2) % 66;
        int row = i / 264;
        int y = y0 + row - 1;
        int xg = x - 1;
        bool ok = (i < IN_ITEMS) && (y >= 0) && (y < 64) && (xg >= 0) && (xg < 64);
        int grp = sub ^ (x & 3) ^ ((x >> 2) & 1);
        gin[it] = ok ? ((y * 64 + xg) * CI + grp * 8) : -1;
    }
    int gw[W_ITERS];
#pragma unroll
    for (int it = 0; it < W_ITERS; ++it) {
        int i = it * NT + tid;
        if (i < W_ITEMS) {
            int sub = i & 3;
            int co = (i >> 2) % CO_BLK;
            int tap = i / (CO_BLK * 4);
            int grp = sub ^ (co & 3) ^ ((co >> 2) & 1);
            gw[it] = (tap * CO_TOTAL + co0 + co) * CI + grp * 8;
        } else gw[it] = 0;
    }

    f32x4 acc[MT][4];
#pragma unroll
    for (int mt = 0; mt < MT; ++mt)
#pragma unroll
        for (int j = 0; j < 4; ++j) acc[mt][j] = (f32x4){0.f, 0.f, 0.f, 0.f};

    for (int chunk = 0; chunk < CHUNKS; ++chunk) {
        const int ci0 = chunk * 32;
        __syncthreads();
#pragma unroll
        for (int it = 0; it < IN_ITERS; ++it) {
            int i0 = it * NT + (tid & ~63);
            if (i0 < IN_PAD) {
                const bf16* gp = (gin[it] >= 0) ? (in + in_base + gin[it] + ci0) : zpage;
                gload16(gp, s_in + (size_t)i0 * 8);
            }
        }
#pragma unroll
        for (int it = 0; it < W_ITERS; ++it) {
            int i0 = it * NT + (tid & ~63);
            if (i0 < W_ITEMS) {
                const bf16* gp = wpk + gw[it] + ci0;
                gload16(gp, s_w + (size_t)i0 * 8);
            }
        }
        __syncthreads();

#pragma unroll
        for (int ky = 0; ky < 3; ++ky) {
#pragma unroll
            for (int kx = 0; kx < 3; ++kx) {
                const int tap = ky * 3 + kx;
                bf16x8 bfrag[4];
#pragma unroll
                for (int j = 0; j < 4; ++j) {
                    int x = j * 16 + n16 + kx;
                    int ps = quad ^ (x & 3) ^ ((x >> 2) & 1);
                    bfrag[j] = *(const bf16x8*)&s_in[((wv + ky) * 66 + x) * 32 + ps * 8];
                }
#pragma unroll
                for (int mt = 0; mt < MT; ++mt) {
                    int mrow = mt * 16 + n16;
                    int ps = quad ^ (mrow & 3) ^ ((mrow >> 2) & 1);
                    bf16x8 afrag = *(const bf16x8*)&s_w[(tap * CO_BLK + mrow) * 32 + ps * 8];
#pragma unroll
                    for (int j = 0; j < 4; ++j)
                        acc[mt][j] = __builtin_amdgcn_mfma_f32_16x16x32_bf16(afrag, bfrag[j], acc[mt][j], 0, 0, 0);
                }
            }
        }
    }

    const int osmp = out_s0 + smp;
#pragma unroll
    for (int j = 0; j < 4; ++j) {
        int pos = (y0 + wv) * 64 + j * 16 + n16;
#pragma unroll
        for (int mt = 0; mt < MT; ++mt) {
            int coutb = co0 + mt * 16 + quad * 4;
            float b0 = 0.f, b1 = 0.f, b2 = 0.f, b3 = 0.f;
            if constexpr (EPI != 1) {
                float4 bv = *(const float4*)&bias[coutb];
                b0 = bv.x; b1 = bv.y; b2 = bv.z; b3 = bv.w;
            }
            float v0 = acc[mt][j][0] + b0;
            float v1 = acc[mt][j][1] + b1;
            float v2 = acc[mt][j][2] + b2;
            float v3 = acc[mt][j][3] + b3;
            if constexpr (EPI == 1 || EPI == 2 || EPI == 3) {
                if constexpr (EPI == 2) {
                    const float* xr = (const float*)res + (size_t)osmp * 131072 + (size_t)coutb * 4096 + pos;
                    v0 += xr[0]; v1 += xr[4096]; v2 += xr[8192]; v3 += xr[12288];
                } else if constexpr (EPI == 3) {
                    v0 = gelu_new(v0); v1 = gelu_new(v1); v2 = gelu_new(v2); v3 = gelu_new(v3);
                }
                ushort4 st;
                st.x = f2bu(v0); st.y = f2bu(v1); st.z = f2bu(v2); st.w = f2bu(v3);
                *(ushort4*)&((bf16*)out)[((size_t)osmp * 4096 + pos) * CO_TOTAL + coutb] = st;
            } else {
                ushort4 rv = *(const ushort4*)&((const bf16*)res)[((size_t)osmp * 4096 + pos) * 32 + coutb];
                v0 += su2f(rv.x); v1 += su2f(rv.y); v2 += su2f(rv.z); v3 += su2f(rv.w);
                float* op = (float*)out + (size_t)osmp * 131072 + (size_t)coutb * 4096 + pos;
                op[0] = v0; op[4096] = v1; op[8192] = v2; op[12288] = v3;
            }
        }
    }
}

// ---------------- stride-2 conv (k,q merged: CO_TOTAL=64) ----------------
template <int CI, int CI_BLK, int CO_TOTAL, int CO_BLK, int S, int EPI>
__global__ __launch_bounds__(256) void conv_mfma(const bf16* __restrict__ in,
                                                 const bf16* __restrict__ wpk,
                                                 const float* __restrict__ bias,
                                                 const void* __restrict__ res,
                                                 void* __restrict__ out,
                                                 int in_s0, int out_s0) {
    constexpr int WO = 64 / S;
    constexpr int HO = 64 / S;
    constexpr int NG = (HO * WO) / 256;
    constexpr int TPR = WO / 16;
    constexpr int MT = CO_BLK / 16;
    constexpr int PHASES = CI / CI_BLK;
    constexpr int KC = CI_BLK / 32;
    constexpr int PAD = CI_BLK + 8;

    __shared__ short s_w[9 * CO_BLK * PAD];

    const int tid = threadIdx.x;
    const int lane = tid & 63;
    const int wv = tid >> 6;
    const int quad = lane >> 4;
    const int n16 = lane & 15;

    const int ng = blockIdx.x % NG;
    const int cg = blockIdx.x / NG;
    const int co0 = cg * CO_BLK;
    const int smp = blockIdx.y;

    f32x4 acc[MT][4];
#pragma unroll
    for (int mt = 0; mt < MT; ++mt)
#pragma unroll
        for (int j = 0; j < 4; ++j) acc[mt][j] = (f32x4){0.f, 0.f, 0.f, 0.f};

    const size_t in_base = (size_t)(in_s0 + smp) * 4096 * CI;

    for (int phase = 0; phase < PHASES; ++phase) {
        const int ci0 = phase * CI_BLK;
        __syncthreads();
        for (int idx = tid; idx < 9 * CO_BLK * CI_BLK / 4; idx += 256) {
            int e = idx * 4;
            int tap = e / (CO_BLK * CI_BLK);
            int rem = e - tap * (CO_BLK * CI_BLK);
            int col = rem / CI_BLK;
            int k = rem - col * CI_BLK;
            const ushort4 src = *(const ushort4*)&wpk[((size_t)tap * CO_TOTAL + co0 + col) * CI + ci0 + k];
            *(ushort4*)&s_w[(tap * CO_BLK + col) * PAD + k] = src;
        }
        __syncthreads();

#pragma unroll
        for (int ky = 0; ky < 3; ++ky) {
#pragma unroll
            for (int kx = 0; kx < 3; ++kx) {
                const int tap = ky * 3 + kx;
                bf16x8 bfrag[KC][4];
#pragma unroll
                for (int kc = 0; kc < KC; ++kc) {
#pragma unroll
                    for (int j = 0; j < 4; ++j) {
                        int tile = ng * 16 + wv * 4 + j;
                        int yo = tile / TPR;
                        int xo = (tile % TPR) * 16;
                        int xi = (xo + n16) * S + kx - 1;
                        int yi = yo * S + ky - 1;
                        bool valid = (xi >= 0) && (xi < 64) && (yi >= 0) && (yi < 64);
                        uint4 u;
                        if (valid)
                            u = *(const uint4*)&in[in_base + ((size_t)yi * 64 + xi) * CI + ci0 + kc * 32 + quad * 8];
                        else
                            u = make_uint4(0u, 0u, 0u, 0u);
                        __builtin_memcpy(&bfrag[kc][j], &u, 16);
                    }
                }
#pragma unroll
                for (int kc = 0; kc < KC; ++kc) {
#pragma unroll
                    for (int mt = 0; mt < MT; ++mt) {
                        bf16x8 afrag = *(const bf16x8*)&s_w[(tap * CO_BLK + mt * 16 + n16) * PAD + kc * 32 + quad * 8];
#pragma unroll
                        for (int j = 0; j < 4; ++j)
                            acc[mt][j] = __builtin_amdgcn_mfma_f32_16x16x32_bf16(afrag, bfrag[kc][j], acc[mt][j], 0, 0, 0);
                    }
                }
            }
        }
    }

    const int osmp = out_s0 + smp;
#pragma unroll
    for (int j = 0; j < 4; ++j) {
        int tile = ng * 16 + wv * 4 + j;
        int yo = tile / TPR;
        int xo = (tile % TPR) * 16;
        int pos = yo * WO + xo + n16;
#pragma unroll
        for (int mt = 0; mt < MT; ++mt) {
            int coutb = co0 + mt * 16 + quad * 4;
            ushort4 st;
            st.x = f2bu(acc[mt][j][0]); st.y = f2bu(acc[mt][j][1]);
            st.z = f2bu(acc[mt][j][2]); st.w = f2bu(acc[mt][j][3]);
            *(ushort4*)&((bf16*)out)[((size_t)osmp * HO * WO + pos) * CO_TOTAL + coutb] = st;
        }
    }
}

// ---------------- attention scores + softmax : fused MFMA ----------------
// KQ merged layout: [bt][1024 p][64 c]; K = c 0..31, Q = c 32..63.
__global__ __launch_bounds__(256) void attn_scores_mfma(const bf16* __restrict__ KQ,
                                                        bf16* __restrict__ att) {
    __shared__ float red[4][32][33];
    __shared__ float sc[32][33];
    const int tid = threadIdx.x;
    const int lane = tid & 63;
    const int wv = tid >> 6;
    const int quad = lane >> 4;
    const int n16 = lane & 15;
    const int h = blockIdx.x & 7;
    const int b = blockIdx.x >> 3;
    const size_t base = (size_t)b * 32 * 65536 + (size_t)h * 4;

    f32x4 acc[2][2];
#pragma unroll
    for (int mt = 0; mt < 2; ++mt)
#pragma unroll
        for (int nt = 0; nt < 2; ++nt) acc[mt][nt] = (f32x4){0.f, 0.f, 0.f, 0.f};

    for (int kc = 0; kc < 32; ++kc) {
        const int p0 = wv * 256 + kc * 8 + quad * 2;
        bf16x8 afrag[2], bfrag[2];
#pragma unroll
        for (int mt = 0; mt < 2; ++mt) {
            const bf16* qp = &KQ[base + 32 + (size_t)(mt * 16 + n16) * 65536 + (size_t)p0 * 64];
            uint2 lo = *(const uint2*)qp;
            uint2 hi = *(const uint2*)(qp + 64);
            uint4 u = make_uint4(lo.x, lo.y, hi.x, hi.y);
            __builtin_memcpy(&afrag[mt], &u, 16);
        }
#pragma unroll
        for (int nt = 0; nt < 2; ++nt) {
            const bf16* kp = &KQ[base + (size_t)(nt * 16 + n16) * 65536 + (size_t)p0 * 64];
            uint2 lo = *(const uint2*)kp;
            uint2 hi = *(const uint2*)(kp + 64);
            uint4 u = make_uint4(lo.x, lo.y, hi.x, hi.y);
            __builtin_memcpy(&bfrag[nt], &u, 16);
        }
#pragma unroll
        for (int mt = 0; mt < 2; ++mt)
#pragma unroll
            for (int nt = 0; nt < 2; ++nt)
                acc[mt][nt] = __builtin_amdgcn_mfma_f32_16x16x32_bf16(afrag[mt], bfrag[nt], acc[mt][nt], 0, 0, 0);
    }
#pragma unroll
    for (int mt = 0; mt < 2; ++mt)
#pragma unroll
        for (int nt = 0; nt < 2; ++nt)
#pragma unroll
            for (int r = 0; r < 4; ++r)
                red[wv][mt * 16 + quad * 4 + r][nt * 16 + n16] = acc[mt][nt][r];
    __syncthreads();
    for (int i = tid; i < 1024; i += 256) {
        int t = i >> 5, s = i & 31;
        sc[t][s] = (red[0][t][s] + red[1][t][s] + red[2][t][s] + red[3][t][s]) * (1.0f / 64.0f);
    }
    __syncthreads();
    if (tid < 32) {
        float mx = -1e30f;
        for (int s2 = 0; s2 < 32; ++s2) mx = fmaxf(mx, sc[tid][s2]);
        float sum = 0.f;
        for (int s2 = 0; s2 < 32; ++s2) sum += expf(sc[tid][s2] - mx);
        float inv = 1.f / sum;
        bf16* arow = &att[((size_t)blockIdx.x * 32 + tid) * 32];
        for (int s2 = 0; s2 < 32; ++s2) arow[s2] = f2b(expf(sc[tid][s2] - mx) * inv);
    }
}

// ---------------- y = att @ v : MFMA with fused in-LDS V transpose ----------
__global__ __launch_bounds__(256) void attn_apply_mfma(const bf16* __restrict__ att,
                                                       const bf16* __restrict__ V,
                                                       bf16* __restrict__ Y) {
    __shared__ short vlds[512 * 40];
    __shared__ short ylds[32 * 512];
    const int tid = threadIdx.x;
    const int lane = tid & 63;
    const int wv = tid >> 6;
    const int quad = lane >> 4;
    const int n16 = lane & 15;
    const int pb = blockIdx.x;
    const int b = blockIdx.y;

    for (int l = 0; l < 8; ++l) {
        int u = l * 256 + tid;
        int s = u >> 6;
        int col8 = (u & 63) * 8;
        uint4 v = *(const uint4*)&V[(((size_t)(b * 32 + s) * 4096 + pb * 16) * 32) + col8];
        unsigned short us[8];
        __builtin_memcpy(us, &v, 16);
#pragma unroll
        for (int j = 0; j < 8; ++j) {
            int idx = col8 + j;
            int p = idx >> 5, c = idx & 31;
            int row = ((c >> 2) * 16 + p) * 4 + (c & 3);
            vlds[row * 40 + s] = (short)us[j];
        }
    }
    __syncthreads();

    const int e = wv * 16 + n16;
    const int p = e >> 2, cl = e & 3;
    for (int h = 0; h < 8; ++h) {
        bf16x8 bfrag = *(const bf16x8*)&vlds[(h * 64 + e) * 40 + quad * 8];
        const int c = h * 4 + cl;
#pragma unroll
        for (int mt = 0; mt < 2; ++mt) {
            bf16x8 afrag = *(const bf16x8*)&att[((size_t)(b * 8 + h) * 32 + mt * 16 + n16) * 32 + quad * 8];
            f32x4 d = __builtin_amdgcn_mfma_f32_16x16x32_bf16(afrag, bfrag,
                                                              (f32x4){0.f, 0.f, 0.f, 0.f}, 0, 0, 0);
#pragma unroll
            for (int r = 0; r < 4; ++r) {
                int t = mt * 16 + quad * 4 + r;
                ylds[t * 512 + p * 32 + c] = (short)f2bu(d[r]);
            }
        }
    }
    __syncthreads();

    for (int l = 0; l < 8; ++l) {
        int u = l * 256 + tid;
        int t = u >> 6;
        int col8 = (u & 63) * 8;
        *(uint4*)&Y[(((size_t)(b * 32 + t) * 4096 + pb * 16) * 32) + col8] =
            *(const uint4*)&ylds[t * 512 + col8];
    }
}

extern "C" void kernel_launch(void* const* d_in, const int* in_sizes, int n_in,
                              void* d_out, int out_size, void* d_ws, size_t ws_size,
                              hipStream_t stream) {
    const float* x   = (const float*)d_in[0];
    const float* n1g = (const float*)d_in[1];
    const float* n1b = (const float*)d_in[2];
    const float* n2g = (const float*)d_in[3];
    const float* n2b = (const float*)d_in[4];
    const float* Wk  = (const float*)d_in[5];
    const float* Wq  = (const float*)d_in[6];
    const float* Wv  = (const float*)d_in[7];
    const float* Wo  = (const float*)d_in[8];
    const float* bo  = (const float*)d_in[9];
    const float* Wm1 = (const float*)d_in[10];
    const float* bm1 = (const float*)d_in[11];
    const float* Wm2 = (const float*)d_in[12];
    const float* bm2 = (const float*)d_in[13];

    char* ws = (char*)d_ws;
    const size_t A_OFF = 0;
    const size_t B_OFF = 33554432;
    const size_t D_OFF = 67108864;
    const size_t E_OFF = 67239936;
    const size_t F_OFF = 67461120;
    const size_t C_OFF = 68519936;

    bf16*  xn   = (bf16*)(ws + A_OFF);
    bf16*  Yb   = (bf16*)(ws + A_OFF);
    bf16*  xn2  = (bf16*)(ws + A_OFF);
    bf16*  Vb   = (bf16*)(ws + B_OFF);
    bf16*  X1   = (bf16*)(ws + B_OFF);
    bf16*  attbf = (bf16*)(ws + D_OFF);
    bf16*  wpk_kq = (bf16*)(ws + E_OFF);            // 9*64*32*2 = 36864 B
    bf16*  wpk_v  = (bf16*)(ws + E_OFF + 36864);
    bf16*  wpk_o  = (bf16*)(ws + E_OFF + 55296);
    bf16*  wpk_m1 = (bf16*)(ws + E_OFF + 73728);
    bf16*  wpk_m2 = (bf16*)(ws + E_OFF + 147456);
    float* g2t  = (float*)(ws + F_OFF);
    float* b2t  = (float*)(ws + F_OFF + 524288);
    float2* spart = (float2*)(ws + F_OFF + 1048576);
    float2* stats = (float2*)(ws + F_OFF + 1056768);
    bf16*  zpg  = (bf16*)(ws + F_OFF + 1057792);    // 256 B zero page
    bf16*  KQb  = (bf16*)(ws + C_OFF);              // [128][1024][64] bf16 = 16 MB
    bf16*  Hb   = (bf16*)(ws + C_OFF);

    const size_t HB_PER_SAMPLE = 1048576;
    int chunk = 128;
    if (ws_size < C_OFF + 128 * HB_PER_SAMPLE) {
        size_t avail = (ws_size > C_OFF) ? (ws_size - C_OFF) : HB_PER_SAMPLE;
        chunk = (int)(avail / HB_PER_SAMPLE);
        if (chunk < 1) chunk = 1;
        if (chunk > 128) chunk = 128;
    }

    // 0. pack weights (k,q merged); transpose LN2 g/b; zero page
    pack_w<<<36, 256, 0, stream>>>(Wk, wpk_kq, 32, 32, 64, 0);
    pack_w<<<36, 256, 0, stream>>>(Wq, wpk_kq, 32, 32, 64, 32);
    pack_w<<<36, 256, 0, stream>>>(Wv, wpk_v, 32, 32, 32, 0);
    pack_w<<<36, 256, 0, stream>>>(Wo, wpk_o, 32, 32, 32, 0);
    pack_w<<<144, 256, 0, stream>>>(Wm1, wpk_m1, 128, 32, 128, 0);
    pack_w<<<144, 256, 0, stream>>>(Wm2, wpk_m2, 32, 128, 32, 0);
    gtrans_k<<<1024, 256, 0, stream>>>(n2g, n2b, g2t, b2t);
    zero_page<<<1, 64, 0, stream>>>((float*)zpg);

    // 1. LN1: x (NCHW f32) -> xn (NHWC bf16)
    ln_part<float><<<dim3(8, 128), 256, 0, stream>>>(x, spart);
    ln_fin<<<1, 128, 0, stream>>>(spart, stats);
    ln1_norm_t<<<dim3(32, 128), 256, 0, stream>>>(x, n1g, n1b, stats, xn);
    // 2-3. k+q merged (stride 2, CO=64), v (stride 1 LDS, now 8-row)
    conv_mfma<32, 32, 64, 64, 2, 1><<<dim3(4, 128), 256, 0, stream>>>(xn, wpk_kq, nullptr, nullptr, KQb, 0, 0);
    conv_lds<32, 32, 32, 1, 8><<<dim3(8, 128), 512, 0, stream>>>(xn, wpk_v, nullptr, nullptr, Vb, zpg, 0, 0);
    // 5. attention scores + softmax (fused MFMA, merged KQ input)
    attn_scores_mfma<<<32, 256, 0, stream>>>(KQb, attbf);
    // 6. y = att @ v
    attn_apply_mfma<<<dim3(256, 4), 256, 0, stream>>>(attbf, Vb, Yb);
    // 7. Wo conv + bias + residual x -> X1 (now 8-row)
    conv_lds<32, 32, 32, 2, 8><<<dim3(8, 128), 512, 0, stream>>>(Yb, wpk_o, bo, x, X1, zpg, 0, 0);
    // 8. LN2
    ln_part<bf16><<<dim3(8, 128), 256, 0, stream>>>(X1, spart);
    ln_fin<<<1, 128, 0, stream>>>(spart, stats);
    ln2_norm<<<dim3(64, 128), 256, 0, stream>>>(X1, g2t, b2t, stats, xn2);
    // 9-10. mixer: 8-row blocks + async global_load_lds staging + cheap GELU
    for (int s0 = 0; s0 < 128; s0 += chunk) {
        int n = (128 - s0 < chunk) ? (128 - s0) : chunk;
        conv_lds<32, 128, 64, 3, 8><<<dim3(16, n), 512, 0, stream>>>(xn2, wpk_m1, bm1, nullptr, Hb, zpg, s0, 0);
        conv_lds<128, 32, 32, 4, 8><<<dim3(8, n), 512, 0, stream>>>(Hb, wpk_m2, bm2, X1, (float*)d_out, zpg, 0, s0);
    }
}

// Round 11
// 458.118 us; speedup vs baseline: 1.0690x; 1.0690x over previous
//
#include <hip/hip_runtime.h>
#include <hip/hip_bf16.h>

using bf16 = __hip_bfloat16;
typedef short bf16x8 __attribute__((ext_vector_type(8)));
typedef float f32x4 __attribute__((ext_vector_type(4)));

#define AS1 __attribute__((address_space(1)))
#define AS3 __attribute__((address_space(3)))

__device__ inline float b2f(bf16 h) { return __bfloat162float(h); }
__device__ inline bf16 f2b(float f) { return __float2bfloat16(f); }
__device__ inline unsigned short f2bu(float f) {
    bf16 h = __float2bfloat16(f);
    unsigned short u;
    __builtin_memcpy(&u, &h, 2);
    return u;
}
__device__ inline float su2f(unsigned short u) {
    unsigned v = ((unsigned)u) << 16;
    return __uint_as_float(v);
}
// async global->LDS, 16B per lane, LDS dest = wave-uniform base + lane*16
__device__ inline void gload16(const bf16* gp, short* lp) {
    __builtin_amdgcn_global_load_lds((const AS1 void*)gp, (AS3 void*)lp, 16, 0, 0);
}
__device__ inline float fast_rcp(float a) {
#if __has_builtin(__builtin_amdgcn_rcpf)
    return __builtin_amdgcn_rcpf(a);   // v_rcp_f32, 1 instr, ~1ulp
#else
    return 1.0f / a;
#endif
}
// NewGELU. x * rcp(1 + exp2(-c2*(x+a*x^3))), c2 = 2*sqrt(2/pi)*log2(e).
__device__ inline float gelu_new(float x) {
    float x3 = x * x * x;
    float z = -2.3022082f * __builtin_fmaf(0.044715f, x3, x);
    float e = exp2f(z);                // single v_exp_f32
    return x * fast_rcp(1.0f + e);
}

// ---------------- merged setup: all weight packs + g/b transpose + zero page -
// One launch replaces 8. Task decoded from flat index.
__device__ inline void pack_one(const float* w, bf16* wpk, int i,
                                int CO, int CI, int CO_TOTAL, int co_off) {
    int tap = i % 9;
    int ci = (i / 9) % CI;
    int co = i / (9 * CI);
    wpk[((size_t)tap * CO_TOTAL + co_off + co) * CI + ci] = f2b(w[i]);
}
__global__ __launch_bounds__(256) void setup_all(const float* __restrict__ Wk,
                                                 const float* __restrict__ Wq,
                                                 const float* __restrict__ Wv,
                                                 const float* __restrict__ Wo,
                                                 const float* __restrict__ Wm1,
                                                 const float* __restrict__ Wm2,
                                                 const float* __restrict__ n2g,
                                                 const float* __restrict__ n2b,
                                                 bf16* __restrict__ wpk_kq,
                                                 bf16* __restrict__ wpk_v,
                                                 bf16* __restrict__ wpk_o,
                                                 bf16* __restrict__ wpk_m1,
                                                 bf16* __restrict__ wpk_m2,
                                                 float* __restrict__ gt,
                                                 float* __restrict__ bt,
                                                 float* __restrict__ zp) {
    int i = blockIdx.x * 256 + threadIdx.x;
    if (i < 9216)            pack_one(Wk, wpk_kq, i, 32, 32, 64, 0);
    else if (i < 18432)      pack_one(Wq, wpk_kq, i - 9216, 32, 32, 64, 32);
    else if (i < 27648)      pack_one(Wv, wpk_v, i - 18432, 32, 32, 32, 0);
    else if (i < 36864)      pack_one(Wo, wpk_o, i - 27648, 32, 32, 32, 0);
    else if (i < 73728)      pack_one(Wm1, wpk_m1, i - 36864, 128, 32, 128, 0);
    else if (i < 110592)     pack_one(Wm2, wpk_m2, i - 73728, 32, 128, 32, 0);
    else if (i < 110656)     zp[i - 110592] = 0.f;
    else if (i < 372800) {
        int j = i - 110656;
        int sel = j >> 17;
        int o = j & 131071;
        int p = o >> 5, c = o & 31;
        int src = c * 4096 + p;
        if (sel == 0) gt[o] = n2g[src];
        else          bt[o] = n2b[src];
    }
}

// ---------------- LN partial reduce (f32 input only now): grid (8, 128) -----
__global__ __launch_bounds__(256) void ln_part_f32(const float* __restrict__ xin,
                                                   float2* __restrict__ spart) {
    const int tid = threadIdx.x;
    const int sample = blockIdx.y, seg = blockIdx.x;
    const size_t base = (size_t)sample * 131072 + seg * 16384;
    float sum = 0.f, ss = 0.f;
    const float4* p = (const float4*)(xin + base);
    for (int l = 0; l < 16; ++l) {
        float4 v = p[l * 256 + tid];
        sum += v.x + v.y + v.z + v.w;
        ss += v.x * v.x + v.y * v.y + v.z * v.z + v.w * v.w;
    }
    __shared__ float rs[256], rs2[256];
    rs[tid] = sum; rs2[tid] = ss;
    __syncthreads();
    for (int off = 128; off > 0; off >>= 1) {
        if (tid < off) { rs[tid] += rs[tid + off]; rs2[tid] += rs2[tid + off]; }
        __syncthreads();
    }
    if (tid == 0) spart[sample * 8 + seg] = make_float2(rs[0], rs2[0]);
}

// ---------------- LN finalize ----------------
__global__ __launch_bounds__(128) void ln_fin(const float2* __restrict__ spart,
                                              float2* __restrict__ stats) {
    int t = threadIdx.x;
    float s = 0.f, ss = 0.f;
    for (int j = 0; j < 8; ++j) {
        float2 v = spart[t * 8 + j];
        s += v.x; ss += v.y;
    }
    float m = s / 131072.f;
    float var = ss / 131072.f - m * m;
    stats[t] = make_float2(m, rsqrtf(var + 1e-5f));
}

// ---------------- LN1 normalize + NCHW->NHWC transpose ----------------
__global__ __launch_bounds__(256) void ln1_norm_t(const float* __restrict__ x,
                                                  const float* __restrict__ g,
                                                  const float* __restrict__ bb,
                                                  const float2* __restrict__ stats,
                                                  bf16* __restrict__ out) {
    __shared__ float tile[32][129];
    const int tid = threadIdx.x;
    const int sample = blockIdx.y;
    const int p0 = blockIdx.x * 128;
    float2 st = stats[sample];
    const float m = st.x, r = st.y;
    const size_t xb = (size_t)sample * 131072;
    for (int k = 0; k < 16; ++k) {
        int idx = k * 256 + tid;
        int c = idx >> 7, p = idx & 127;
        int gi = c * 4096 + p0 + p;
        float v = x[xb + gi];
        tile[c][p] = (v - m) * r * g[gi] + bb[gi];
    }
    __syncthreads();
    for (int k = 0; k < 8; ++k) {
        int idx = k * 256 + tid;
        int p = idx >> 4, c2 = (idx & 15) * 2;
        unsigned lo = (unsigned)f2bu(tile[c2][p]);
        unsigned hi = (unsigned)f2bu(tile[c2 + 1][p]);
        *(unsigned*)&out[xb + (size_t)(p0 + p) * 32 + c2] = lo | (hi << 16);
    }
}

// ---------------- LN2 normalize, NHWC linear ----------------
__global__ __launch_bounds__(256) void ln2_norm(const bf16* __restrict__ xin,
                                                const float* __restrict__ gt,
                                                const float* __restrict__ bt,
                                                const float2* __restrict__ stats,
                                                bf16* __restrict__ out) {
    const int tid = threadIdx.x;
    const int sample = blockIdx.y;
    float2 st = stats[sample];
    const float m = st.x, r = st.y;
    int i0 = (blockIdx.x * 256 + tid) * 8;
    const size_t base = (size_t)sample * 131072 + i0;
    uint4 u = *(const uint4*)&xin[base];
    float4 g0 = *(const float4*)&gt[i0];
    float4 g1 = *(const float4*)&gt[i0 + 4];
    float4 b0 = *(const float4*)&bt[i0];
    float4 b1 = *(const float4*)&bt[i0 + 4];
    unsigned w[4] = {u.x, u.y, u.z, u.w};
    float gv[8] = {g0.x, g0.y, g0.z, g0.w, g1.x, g1.y, g1.z, g1.w};
    float bv[8] = {b0.x, b0.y, b0.z, b0.w, b1.x, b1.y, b1.z, b1.w};
    unsigned o[4];
#pragma unroll
    for (int j = 0; j < 4; ++j) {
        float lo = __uint_as_float(w[j] << 16);
        float hi = __uint_as_float(w[j] & 0xffff0000u);
        lo = (lo - m) * r * gv[2 * j] + bv[2 * j];
        hi = (hi - m) * r * gv[2 * j + 1] + bv[2 * j + 1];
        o[j] = (unsigned)f2bu(lo) | ((unsigned)f2bu(hi) << 16);
    }
    uint4 st4 = make_uint4(o[0], o[1], o[2], o[3]);
    *(uint4*)&out[base] = st4;
}

// ---------------- stride-1 conv: async global_load_lds staging --------------
// EPI==2 additionally reduces LN2 partial stats over its X1 outputs (f32,
// pre-bf16-rounding) and writes spart[smp*8+ng] — its grid (8 ng x 128 smp)
// exactly partitions each sample, replacing the ln_part<bf16> pass.
template <int CI, int CO_TOTAL, int CO_BLK, int EPI, int ROWS = 4>
__global__ __launch_bounds__(ROWS * 64) void conv_lds(const bf16* __restrict__ in,
                                                      const bf16* __restrict__ wpk,
                                                      const float* __restrict__ bias,
                                                      const void* __restrict__ res,
                                                      void* __restrict__ out,
                                                      const bf16* __restrict__ zpage,
                                                      float2* __restrict__ spart_out,
                                                      int in_s0, int out_s0) {
    constexpr int CHUNKS = CI / 32;
    constexpr int MT = CO_BLK / 16;
    constexpr int NG = 64 / ROWS;
    constexpr int NT = ROWS * 64;
    constexpr int HR = ROWS + 2;
    constexpr int IN_ITEMS = HR * 66 * 4;
    constexpr int IN_PAD = ((IN_ITEMS + 63) / 64) * 64;
    constexpr int IN_ITERS = (IN_PAD + NT - 1) / NT;
    constexpr int W_ITEMS = 9 * CO_BLK * 4;
    constexpr int W_ITERS = (W_ITEMS + NT - 1) / NT;

    __shared__ short s_in[IN_PAD * 8];
    __shared__ short s_w[9 * CO_BLK * 32];
    __shared__ float rsum[EPI == 2 ? NT : 1];
    __shared__ float rss[EPI == 2 ? NT : 1];

    const int tid = threadIdx.x;
    const int lane = tid & 63;
    const int wv = tid >> 6;
    const int quad = lane >> 4;
    const int n16 = lane & 15;

    const int ng = blockIdx.x % NG;
    const int cg = blockIdx.x / NG;
    const int co0 = cg * CO_BLK;
    const int smp = blockIdx.y;
    const int y0 = ng * ROWS;

    const size_t in_base = (size_t)(in_s0 + smp) * 4096 * CI;

    int gin[IN_ITERS];
#pragma unroll
    for (int it = 0; it < IN_ITERS; ++it) {
        int i = it * NT + tid;
        int sub = i & 3;
        int x = (i >> 2) % 66;
        int row = i / 264;
        int y = y0 + row - 1;
        int xg = x - 1;
        bool ok = (i < IN_ITEMS) && (y >= 0) && (y < 64) && (xg >= 0) && (xg < 64);
        int grp = sub ^ (x & 3) ^ ((x >> 2) & 1);
        gin[it] = ok ? ((y * 64 + xg) * CI + grp * 8) : -1;
    }
    int gw[W_ITERS];
#pragma unroll
    for (int it = 0; it < W_ITERS; ++it) {
        int i = it * NT + tid;
        if (i < W_ITEMS) {
            int sub = i & 3;
            int co = (i >> 2) % CO_BLK;
            int tap = i / (CO_BLK * 4);
            int grp = sub ^ (co & 3) ^ ((co >> 2) & 1);
            gw[it] = (tap * CO_TOTAL + co0 + co) * CI + grp * 8;
        } else gw[it] = 0;
    }

    f32x4 acc[MT][4];
#pragma unroll
    for (int mt = 0; mt < MT; ++mt)
#pragma unroll
        for (int j = 0; j < 4; ++j) acc[mt][j] = (f32x4){0.f, 0.f, 0.f, 0.f};

    for (int chunk = 0; chunk < CHUNKS; ++chunk) {
        const int ci0 = chunk * 32;
        __syncthreads();
#pragma unroll
        for (int it = 0; it < IN_ITERS; ++it) {
            int i0 = it * NT + (tid & ~63);
            if (i0 < IN_PAD) {
                const bf16* gp = (gin[it] >= 0) ? (in + in_base + gin[it] + ci0) : zpage;
                gload16(gp, s_in + (size_t)i0 * 8);
            }
        }
#pragma unroll
        for (int it = 0; it < W_ITERS; ++it) {
            int i0 = it * NT + (tid & ~63);
            if (i0 < W_ITEMS) {
                const bf16* gp = wpk + gw[it] + ci0;
                gload16(gp, s_w + (size_t)i0 * 8);
            }
        }
        __syncthreads();

#pragma unroll
        for (int ky = 0; ky < 3; ++ky) {
#pragma unroll
            for (int kx = 0; kx < 3; ++kx) {
                const int tap = ky * 3 + kx;
                bf16x8 bfrag[4];
#pragma unroll
                for (int j = 0; j < 4; ++j) {
                    int x = j * 16 + n16 + kx;
                    int ps = quad ^ (x & 3) ^ ((x >> 2) & 1);
                    bfrag[j] = *(const bf16x8*)&s_in[((wv + ky) * 66 + x) * 32 + ps * 8];
                }
#pragma unroll
                for (int mt = 0; mt < MT; ++mt) {
                    int mrow = mt * 16 + n16;
                    int ps = quad ^ (mrow & 3) ^ ((mrow >> 2) & 1);
                    bf16x8 afrag = *(const bf16x8*)&s_w[(tap * CO_BLK + mrow) * 32 + ps * 8];
#pragma unroll
                    for (int j = 0; j < 4; ++j)
                        acc[mt][j] = __builtin_amdgcn_mfma_f32_16x16x32_bf16(afrag, bfrag[j], acc[mt][j], 0, 0, 0);
                }
            }
        }
    }

    const int osmp = out_s0 + smp;
    float lsum = 0.f, lss = 0.f;
#pragma unroll
    for (int j = 0; j < 4; ++j) {
        int pos = (y0 + wv) * 64 + j * 16 + n16;
#pragma unroll
        for (int mt = 0; mt < MT; ++mt) {
            int coutb = co0 + mt * 16 + quad * 4;
            float b0 = 0.f, b1 = 0.f, b2 = 0.f, b3 = 0.f;
            if constexpr (EPI != 1) {
                float4 bv = *(const float4*)&bias[coutb];
                b0 = bv.x; b1 = bv.y; b2 = bv.z; b3 = bv.w;
            }
            float v0 = acc[mt][j][0] + b0;
            float v1 = acc[mt][j][1] + b1;
            float v2 = acc[mt][j][2] + b2;
            float v3 = acc[mt][j][3] + b3;
            if constexpr (EPI == 1 || EPI == 2 || EPI == 3) {
                if constexpr (EPI == 2) {
                    const float* xr = (const float*)res + (size_t)osmp * 131072 + (size_t)coutb * 4096 + pos;
                    v0 += xr[0]; v1 += xr[4096]; v2 += xr[8192]; v3 += xr[12288];
                    lsum += v0 + v1 + v2 + v3;
                    lss += v0 * v0 + v1 * v1 + v2 * v2 + v3 * v3;
                } else if constexpr (EPI == 3) {
                    v0 = gelu_new(v0); v1 = gelu_new(v1); v2 = gelu_new(v2); v3 = gelu_new(v3);
                }
                ushort4 st;
                st.x = f2bu(v0); st.y = f2bu(v1); st.z = f2bu(v2); st.w = f2bu(v3);
                *(ushort4*)&((bf16*)out)[((size_t)osmp * 4096 + pos) * CO_TOTAL + coutb] = st;
            } else {
                ushort4 rv = *(const ushort4*)&((const bf16*)res)[((size_t)osmp * 4096 + pos) * 32 + coutb];
                v0 += su2f(rv.x); v1 += su2f(rv.y); v2 += su2f(rv.z); v3 += su2f(rv.w);
                float* op = (float*)out + (size_t)osmp * 131072 + (size_t)coutb * 4096 + pos;
                op[0] = v0; op[4096] = v1; op[8192] = v2; op[12288] = v3;
            }
        }
    }

    if constexpr (EPI == 2) {
        rsum[tid] = lsum; rss[tid] = lss;
        __syncthreads();
        for (int off = NT / 2; off > 0; off >>= 1) {
            if (tid < off) { rsum[tid] += rsum[tid + off]; rss[tid] += rss[tid + off]; }
            __syncthreads();
        }
        if (tid == 0) spart_out[smp * 8 + ng] = make_float2(rsum[0], rss[0]);
    }
}

// ---------------- stride-2 conv (k,q merged: CO_TOTAL=64) ----------------
template <int CI, int CI_BLK, int CO_TOTAL, int CO_BLK, int S, int EPI>
__global__ __launch_bounds__(256) void conv_mfma(const bf16* __restrict__ in,
                                                 const bf16* __restrict__ wpk,
                                                 const float* __restrict__ bias,
                                                 const void* __restrict__ res,
                                                 void* __restrict__ out,
                                                 int in_s0, int out_s0) {
    constexpr int WO = 64 / S;
    constexpr int HO = 64 / S;
    constexpr int NG = (HO * WO) / 256;
    constexpr int TPR = WO / 16;
    constexpr int MT = CO_BLK / 16;
    constexpr int PHASES = CI / CI_BLK;
    constexpr int KC = CI_BLK / 32;
    constexpr int PAD = CI_BLK + 8;

    __shared__ short s_w[9 * CO_BLK * PAD];

    const int tid = threadIdx.x;
    const int lane = tid & 63;
    const int wv = tid >> 6;
    const int quad = lane >> 4;
    const int n16 = lane & 15;

    const int ng = blockIdx.x % NG;
    const int cg = blockIdx.x / NG;
    const int co0 = cg * CO_BLK;
    const int smp = blockIdx.y;

    f32x4 acc[MT][4];
#pragma unroll
    for (int mt = 0; mt < MT; ++mt)
#pragma unroll
        for (int j = 0; j < 4; ++j) acc[mt][j] = (f32x4){0.f, 0.f, 0.f, 0.f};

    const size_t in_base = (size_t)(in_s0 + smp) * 4096 * CI;

    for (int phase = 0; phase < PHASES; ++phase) {
        const int ci0 = phase * CI_BLK;
        __syncthreads();
        for (int idx = tid; idx < 9 * CO_BLK * CI_BLK / 4; idx += 256) {
            int e = idx * 4;
            int tap = e / (CO_BLK * CI_BLK);
            int rem = e - tap * (CO_BLK * CI_BLK);
            int col = rem / CI_BLK;
            int k = rem - col * CI_BLK;
            const ushort4 src = *(const ushort4*)&wpk[((size_t)tap * CO_TOTAL + co0 + col) * CI + ci0 + k];
            *(ushort4*)&s_w[(tap * CO_BLK + col) * PAD + k] = src;
        }
        __syncthreads();

#pragma unroll
        for (int ky = 0; ky < 3; ++ky) {
#pragma unroll
            for (int kx = 0; kx < 3; ++kx) {
                const int tap = ky * 3 + kx;
                bf16x8 bfrag[KC][4];
#pragma unroll
                for (int kc = 0; kc < KC; ++kc) {
#pragma unroll
                    for (int j = 0; j < 4; ++j) {
                        int tile = ng * 16 + wv * 4 + j;
                        int yo = tile / TPR;
                        int xo = (tile % TPR) * 16;
                        int xi = (xo + n16) * S + kx - 1;
                        int yi = yo * S + ky - 1;
                        bool valid = (xi >= 0) && (xi < 64) && (yi >= 0) && (yi < 64);
                        uint4 u;
                        if (valid)
                            u = *(const uint4*)&in[in_base + ((size_t)yi * 64 + xi) * CI + ci0 + kc * 32 + quad * 8];
                        else
                            u = make_uint4(0u, 0u, 0u, 0u);
                        __builtin_memcpy(&bfrag[kc][j], &u, 16);
                    }
                }
#pragma unroll
                for (int kc = 0; kc < KC; ++kc) {
#pragma unroll
                    for (int mt = 0; mt < MT; ++mt) {
                        bf16x8 afrag = *(const bf16x8*)&s_w[(tap * CO_BLK + mt * 16 + n16) * PAD + kc * 32 + quad * 8];
#pragma unroll
                        for (int j = 0; j < 4; ++j)
                            acc[mt][j] = __builtin_amdgcn_mfma_f32_16x16x32_bf16(afrag, bfrag[kc][j], acc[mt][j], 0, 0, 0);
                    }
                }
            }
        }
    }

    const int osmp = out_s0 + smp;
#pragma unroll
    for (int j = 0; j < 4; ++j) {
        int tile = ng * 16 + wv * 4 + j;
        int yo = tile / TPR;
        int xo = (tile % TPR) * 16;
        int pos = yo * WO + xo + n16;
#pragma unroll
        for (int mt = 0; mt < MT; ++mt) {
            int coutb = co0 + mt * 16 + quad * 4;
            ushort4 st;
            st.x = f2bu(acc[mt][j][0]); st.y = f2bu(acc[mt][j][1]);
            st.z = f2bu(acc[mt][j][2]); st.w = f2bu(acc[mt][j][3]);
            *(ushort4*)&((bf16*)out)[((size_t)osmp * HO * WO + pos) * CO_TOTAL + coutb] = st;
        }
    }
}

// ---------------- attention scores + softmax : fused MFMA ----------------
// KQ merged layout: [bt][1024 p][64 c]; K = c 0..31, Q = c 32..63.
__global__ __launch_bounds__(256) void attn_scores_mfma(const bf16* __restrict__ KQ,
                                                        bf16* __restrict__ att) {
    __shared__ float red[4][32][33];
    __shared__ float sc[32][33];
    const int tid = threadIdx.x;
    const int lane = tid & 63;
    const int wv = tid >> 6;
    const int quad = lane >> 4;
    const int n16 = lane & 15;
    const int h = blockIdx.x & 7;
    const int b = blockIdx.x >> 3;
    const size_t base = (size_t)b * 32 * 65536 + (size_t)h * 4;

    f32x4 acc[2][2];
#pragma unroll
    for (int mt = 0; mt < 2; ++mt)
#pragma unroll
        for (int nt = 0; nt < 2; ++nt) acc[mt][nt] = (f32x4){0.f, 0.f, 0.f, 0.f};

    for (int kc = 0; kc < 32; ++kc) {
        const int p0 = wv * 256 + kc * 8 + quad * 2;
        bf16x8 afrag[2], bfrag[2];
#pragma unroll
        for (int mt = 0; mt < 2; ++mt) {
            const bf16* qp = &KQ[base + 32 + (size_t)(mt * 16 + n16) * 65536 + (size_t)p0 * 64];
            uint2 lo = *(const uint2*)qp;
            uint2 hi = *(const uint2*)(qp + 64);
            uint4 u = make_uint4(lo.x, lo.y, hi.x, hi.y);
            __builtin_memcpy(&afrag[mt], &u, 16);
        }
#pragma unroll
        for (int nt = 0; nt < 2; ++nt) {
            const bf16* kp = &KQ[base + (size_t)(nt * 16 + n16) * 65536 + (size_t)p0 * 64];
            uint2 lo = *(const uint2*)kp;
            uint2 hi = *(const uint2*)(kp + 64);
            uint4 u = make_uint4(lo.x, lo.y, hi.x, hi.y);
            __builtin_memcpy(&bfrag[nt], &u, 16);
        }
#pragma unroll
        for (int mt = 0; mt < 2; ++mt)
#pragma unroll
            for (int nt = 0; nt < 2; ++nt)
                acc[mt][nt] = __builtin_amdgcn_mfma_f32_16x16x32_bf16(afrag[mt], bfrag[nt], acc[mt][nt], 0, 0, 0);
    }
#pragma unroll
    for (int mt = 0; mt < 2; ++mt)
#pragma unroll
        for (int nt = 0; nt < 2; ++nt)
#pragma unroll
            for (int r = 0; r < 4; ++r)
                red[wv][mt * 16 + quad * 4 + r][nt * 16 + n16] = acc[mt][nt][r];
    __syncthreads();
    for (int i = tid; i < 1024; i += 256) {
        int t = i >> 5, s = i & 31;
        sc[t][s] = (red[0][t][s] + red[1][t][s] + red[2][t][s] + red[3][t][s]) * (1.0f / 64.0f);
    }
    __syncthreads();
    if (tid < 32) {
        float mx = -1e30f;
        for (int s2 = 0; s2 < 32; ++s2) mx = fmaxf(mx, sc[tid][s2]);
        float sum = 0.f;
        for (int s2 = 0; s2 < 32; ++s2) sum += expf(sc[tid][s2] - mx);
        float inv = 1.f / sum;
        bf16* arow = &att[((size_t)blockIdx.x * 32 + tid) * 32];
        for (int s2 = 0; s2 < 32; ++s2) arow[s2] = f2b(expf(sc[tid][s2] - mx) * inv);
    }
}

// ---------------- y = att @ v : MFMA with fused in-LDS V transpose ----------
__global__ __launch_bounds__(256) void attn_apply_mfma(const bf16* __restrict__ att,
                                                       const bf16* __restrict__ V,
                                                       bf16* __restrict__ Y) {
    __shared__ short vlds[512 * 40];
    __shared__ short ylds[32 * 512];
    const int tid = threadIdx.x;
    const int lane = tid & 63;
    const int wv = tid >> 6;
    const int quad = lane >> 4;
    const int n16 = lane & 15;
    const int pb = blockIdx.x;
    const int b = blockIdx.y;

    for (int l = 0; l < 8; ++l) {
        int u = l * 256 + tid;
        int s = u >> 6;
        int col8 = (u & 63) * 8;
        uint4 v = *(const uint4*)&V[(((size_t)(b * 32 + s) * 4096 + pb * 16) * 32) + col8];
        unsigned short us[8];
        __builtin_memcpy(us, &v, 16);
#pragma unroll
        for (int j = 0; j < 8; ++j) {
            int idx = col8 + j;
            int p = idx >> 5, c = idx & 31;
            int row = ((c >> 2) * 16 + p) * 4 + (c & 3);
            vlds[row * 40 + s] = (short)us[j];
        }
    }
    __syncthreads();

    const int e = wv * 16 + n16;
    const int p = e >> 2, cl = e & 3;
    for (int h = 0; h < 8; ++h) {
        bf16x8 bfrag = *(const bf16x8*)&vlds[(h * 64 + e) * 40 + quad * 8];
        const int c = h * 4 + cl;
#pragma unroll
        for (int mt = 0; mt < 2; ++mt) {
            bf16x8 afrag = *(const bf16x8*)&att[((size_t)(b * 8 + h) * 32 + mt * 16 + n16) * 32 + quad * 8];
            f32x4 d = __builtin_amdgcn_mfma_f32_16x16x32_bf16(afrag, bfrag,
                                                              (f32x4){0.f, 0.f, 0.f, 0.f}, 0, 0, 0);
#pragma unroll
            for (int r = 0; r < 4; ++r) {
                int t = mt * 16 + quad * 4 + r;
                ylds[t * 512 + p * 32 + c] = (short)f2bu(d[r]);
            }
        }
    }
    __syncthreads();

    for (int l = 0; l < 8; ++l) {
        int u = l * 256 + tid;
        int t = u >> 6;
        int col8 = (u & 63) * 8;
        *(uint4*)&Y[(((size_t)(b * 32 + t) * 4096 + pb * 16) * 32) + col8] =
            *(const uint4*)&ylds[t * 512 + col8];
    }
}

extern "C" void kernel_launch(void* const* d_in, const int* in_sizes, int n_in,
                              void* d_out, int out_size, void* d_ws, size_t ws_size,
                              hipStream_t stream) {
    const float* x   = (const float*)d_in[0];
    const float* n1g = (const float*)d_in[1];
    const float* n1b = (const float*)d_in[2];
    const float* n2g = (const float*)d_in[3];
    const float* n2b = (const float*)d_in[4];
    const float* Wk  = (const float*)d_in[5];
    const float* Wq  = (const float*)d_in[6];
    const float* Wv  = (const float*)d_in[7];
    const float* Wo  = (const float*)d_in[8];
    const float* bo  = (const float*)d_in[9];
    const float* Wm1 = (const float*)d_in[10];
    const float* bm1 = (const float*)d_in[11];
    const float* Wm2 = (const float*)d_in[12];
    const float* bm2 = (const float*)d_in[13];

    char* ws = (char*)d_ws;
    const size_t A_OFF = 0;
    const size_t B_OFF = 33554432;
    const size_t D_OFF = 67108864;
    const size_t E_OFF = 67239936;
    const size_t F_OFF = 67461120;
    const size_t C_OFF = 68519936;

    bf16*  xn   = (bf16*)(ws + A_OFF);
    bf16*  Yb   = (bf16*)(ws + A_OFF);
    bf16*  xn2  = (bf16*)(ws + A_OFF);
    bf16*  Vb   = (bf16*)(ws + B_OFF);
    bf16*  X1   = (bf16*)(ws + B_OFF);
    bf16*  attbf = (bf16*)(ws + D_OFF);
    bf16*  wpk_kq = (bf16*)(ws + E_OFF);            // 9*64*32*2 = 36864 B
    bf16*  wpk_v  = (bf16*)(ws + E_OFF + 36864);
    bf16*  wpk_o  = (bf16*)(ws + E_OFF + 55296);
    bf16*  wpk_m1 = (bf16*)(ws + E_OFF + 73728);
    bf16*  wpk_m2 = (bf16*)(ws + E_OFF + 147456);
    float* g2t  = (float*)(ws + F_OFF);
    float* b2t  = (float*)(ws + F_OFF + 524288);
    float2* spart = (float2*)(ws + F_OFF + 1048576);
    float2* stats = (float2*)(ws + F_OFF + 1056768);
    bf16*  zpg  = (bf16*)(ws + F_OFF + 1057792);    // 256 B zero page
    bf16*  KQb  = (bf16*)(ws + C_OFF);              // [128][1024][64] bf16 = 16 MB
    bf16*  Hb   = (bf16*)(ws + C_OFF);

    const size_t HB_PER_SAMPLE = 1048576;
    int chunk = 128;
    if (ws_size < C_OFF + 128 * HB_PER_SAMPLE) {
        size_t avail = (ws_size > C_OFF) ? (ws_size - C_OFF) : HB_PER_SAMPLE;
        chunk = (int)(avail / HB_PER_SAMPLE);
        if (chunk < 1) chunk = 1;
        if (chunk > 128) chunk = 128;
    }

    // 0. merged setup: all weight packs + LN2 g/b transpose + zero page
    setup_all<<<1457, 256, 0, stream>>>(Wk, Wq, Wv, Wo, Wm1, Wm2, n2g, n2b,
                                        wpk_kq, wpk_v, wpk_o, wpk_m1, wpk_m2,
                                        g2t, b2t, (float*)zpg);

    // 1. LN1: x (NCHW f32) -> xn (NHWC bf16)
    ln_part_f32<<<dim3(8, 128), 256, 0, stream>>>(x, spart);
    ln_fin<<<1, 128, 0, stream>>>(spart, stats);
    ln1_norm_t<<<dim3(32, 128), 256, 0, stream>>>(x, n1g, n1b, stats, xn);
    // 2-3. k+q merged (stride 2, CO=64), v (stride 1 LDS, 8-row)
    conv_mfma<32, 32, 64, 64, 2, 1><<<dim3(4, 128), 256, 0, stream>>>(xn, wpk_kq, nullptr, nullptr, KQb, 0, 0);
    conv_lds<32, 32, 32, 1, 8><<<dim3(8, 128), 512, 0, stream>>>(xn, wpk_v, nullptr, nullptr, Vb, zpg, nullptr, 0, 0);
    // 5. attention scores + softmax (fused MFMA, merged KQ input)
    attn_scores_mfma<<<32, 256, 0, stream>>>(KQb, attbf);
    // 6. y = att @ v
    attn_apply_mfma<<<dim3(256, 4), 256, 0, stream>>>(attbf, Vb, Yb);
    // 7. Wo conv + bias + residual x -> X1; fused LN2 partial stats -> spart
    conv_lds<32, 32, 32, 2, 8><<<dim3(8, 128), 512, 0, stream>>>(Yb, wpk_o, bo, x, X1, zpg, spart, 0, 0);
    // 8. LN2 finalize + normalize (ln_part<bf16> eliminated by fusion above)
    ln_fin<<<1, 128, 0, stream>>>(spart, stats);
    ln2_norm<<<dim3(64, 128), 256, 0, stream>>>(X1, g2t, b2t, stats, xn2);
    // 9-10. mixer: 8-row blocks + async global_load_lds staging + cheap GELU
    for (int s0 = 0; s0 < 128; s0 += chunk) {
        int n = (128 - s0 < chunk) ? (128 - s0) : chunk;
        conv_lds<32, 128, 64, 3, 8><<<dim3(16, n), 512, 0, stream>>>(xn2, wpk_m1, bm1, nullptr, Hb, zpg, nullptr, s0, 0);
        conv_lds<128, 32, 32, 4, 8><<<dim3(8, n), 512, 0, stream>>>(Hb, wpk_m2, bm2, X1, (float*)d_out, zpg, nullptr, 0, s0);
    }
}

// Round 12
// 450.413 us; speedup vs baseline: 1.0873x; 1.0171x over previous
//
#include <hip/hip_runtime.h>
#include <hip/hip_bf16.h>

using bf16 = __hip_bfloat16;
typedef short bf16x8 __attribute__((ext_vector_type(8)));
typedef float f32x4 __attribute__((ext_vector_type(4)));

#define AS1 __attribute__((address_space(1)))
#define AS3 __attribute__((address_space(3)))

__device__ inline float b2f(bf16 h) { return __bfloat162float(h); }
__device__ inline bf16 f2b(float f) { return __float2bfloat16(f); }
__device__ inline unsigned short f2bu(float f) {
    bf16 h = __float2bfloat16(f);
    unsigned short u;
    __builtin_memcpy(&u, &h, 2);
    return u;
}
__device__ inline float su2f(unsigned short u) {
    unsigned v = ((unsigned)u) << 16;
    return __uint_as_float(v);
}
// async global->LDS, 16B per lane, LDS dest = wave-uniform base + lane*16
__device__ inline void gload16(const bf16* gp, short* lp) {
    __builtin_amdgcn_global_load_lds((const AS1 void*)gp, (AS3 void*)lp, 16, 0, 0);
}
__device__ inline float fast_rcp(float a) {
#if __has_builtin(__builtin_amdgcn_rcpf)
    return __builtin_amdgcn_rcpf(a);
#else
    return 1.0f / a;
#endif
}
// NewGELU: x * rcp(1 + exp2(-c2*(x+a*x^3))), c2 = 2*sqrt(2/pi)*log2(e).
__device__ inline float gelu_new(float x) {
    float x3 = x * x * x;
    float z = -2.3022082f * __builtin_fmaf(0.044715f, x3, x);
    float e = exp2f(z);
    return x * fast_rcp(1.0f + e);
}
// inline LN stats from 8 partials (replaces ln_fin kernel)
__device__ inline float2 ln_stats(const float2* spart, int sample) {
    float s = 0.f, ss = 0.f;
#pragma unroll
    for (int j = 0; j < 8; ++j) {
        float2 v = spart[sample * 8 + j];
        s += v.x; ss += v.y;
    }
    float m = s * (1.f / 131072.f);
    float var = ss * (1.f / 131072.f) - m * m;
    return make_float2(m, rsqrtf(var + 1e-5f));
}

// ---------------- merged setup: weight packs + g/b transpose + zero page ----
__device__ inline void pack_one(const float* w, bf16* wpk, int i,
                                int CO, int CI, int CO_TOTAL, int co_off) {
    int tap = i % 9;
    int ci = (i / 9) % CI;
    int co = i / (9 * CI);
    wpk[((size_t)tap * CO_TOTAL + co_off + co) * CI + ci] = f2b(w[i]);
}
__global__ __launch_bounds__(256) void setup_all(const float* __restrict__ Wk,
                                                 const float* __restrict__ Wq,
                                                 const float* __restrict__ Wv,
                                                 const float* __restrict__ Wo,
                                                 const float* __restrict__ Wm1,
                                                 const float* __restrict__ Wm2,
                                                 const float* __restrict__ n2g,
                                                 const float* __restrict__ n2b,
                                                 bf16* __restrict__ wpk_kq,
                                                 bf16* __restrict__ wpk_v,
                                                 bf16* __restrict__ wpk_o,
                                                 bf16* __restrict__ wpk_m1,
                                                 bf16* __restrict__ wpk_m2,
                                                 float* __restrict__ gt,
                                                 float* __restrict__ bt,
                                                 float* __restrict__ zp) {
    int i = blockIdx.x * 256 + threadIdx.x;
    if (i < 9216)            pack_one(Wk, wpk_kq, i, 32, 32, 64, 0);
    else if (i < 18432)      pack_one(Wq, wpk_kq, i - 9216, 32, 32, 64, 32);
    else if (i < 27648)      pack_one(Wv, wpk_v, i - 18432, 32, 32, 32, 0);
    else if (i < 36864)      pack_one(Wo, wpk_o, i - 27648, 32, 32, 32, 0);
    else if (i < 73728)      pack_one(Wm1, wpk_m1, i - 36864, 128, 32, 128, 0);
    else if (i < 110592)     pack_one(Wm2, wpk_m2, i - 73728, 32, 128, 32, 0);
    else if (i < 110656)     zp[i - 110592] = 0.f;
    else if (i < 372800) {
        int j = i - 110656;
        int sel = j >> 17;
        int o = j & 131071;
        int p = o >> 5, c = o & 31;
        int src = c * 4096 + p;
        if (sel == 0) gt[o] = n2g[src];
        else          bt[o] = n2b[src];
    }
}

// ---------------- LN partial reduce (f32): grid (8, 128) ----------------
__global__ __launch_bounds__(256) void ln_part_f32(const float* __restrict__ xin,
                                                   float2* __restrict__ spart) {
    const int tid = threadIdx.x;
    const int sample = blockIdx.y, seg = blockIdx.x;
    const size_t base = (size_t)sample * 131072 + seg * 16384;
    float sum = 0.f, ss = 0.f;
    const float4* p = (const float4*)(xin + base);
    for (int l = 0; l < 16; ++l) {
        float4 v = p[l * 256 + tid];
        sum += v.x + v.y + v.z + v.w;
        ss += v.x * v.x + v.y * v.y + v.z * v.z + v.w * v.w;
    }
    __shared__ float rs[256], rs2[256];
    rs[tid] = sum; rs2[tid] = ss;
    __syncthreads();
    for (int off = 128; off > 0; off >>= 1) {
        if (tid < off) { rs[tid] += rs[tid + off]; rs2[tid] += rs2[tid + off]; }
        __syncthreads();
    }
    if (tid == 0) spart[sample * 8 + seg] = make_float2(rs[0], rs2[0]);
}

// ---------------- LN1 normalize + NCHW->NHWC transpose (inline stats) -------
__global__ __launch_bounds__(256) void ln1_norm_t(const float* __restrict__ x,
                                                  const float* __restrict__ g,
                                                  const float* __restrict__ bb,
                                                  const float2* __restrict__ spart,
                                                  bf16* __restrict__ out) {
    __shared__ float tile[32][129];
    const int tid = threadIdx.x;
    const int sample = blockIdx.y;
    const int p0 = blockIdx.x * 128;
    float2 st = ln_stats(spart, sample);
    const float m = st.x, r = st.y;
    const size_t xb = (size_t)sample * 131072;
    for (int k = 0; k < 16; ++k) {
        int idx = k * 256 + tid;
        int c = idx >> 7, p = idx & 127;
        int gi = c * 4096 + p0 + p;
        float v = x[xb + gi];
        tile[c][p] = (v - m) * r * g[gi] + bb[gi];
    }
    __syncthreads();
    for (int k = 0; k < 8; ++k) {
        int idx = k * 256 + tid;
        int p = idx >> 4, c2 = (idx & 15) * 2;
        unsigned lo = (unsigned)f2bu(tile[c2][p]);
        unsigned hi = (unsigned)f2bu(tile[c2 + 1][p]);
        *(unsigned*)&out[xb + (size_t)(p0 + p) * 32 + c2] = lo | (hi << 16);
    }
}

// ---------------- LN2 normalize, NHWC linear (inline stats) ----------------
__global__ __launch_bounds__(256) void ln2_norm(const bf16* __restrict__ xin,
                                                const float* __restrict__ gt,
                                                const float* __restrict__ bt,
                                                const float2* __restrict__ spart,
                                                bf16* __restrict__ out) {
    const int tid = threadIdx.x;
    const int sample = blockIdx.y;
    float2 st = ln_stats(spart, sample);
    const float m = st.x, r = st.y;
    int i0 = (blockIdx.x * 256 + tid) * 8;
    const size_t base = (size_t)sample * 131072 + i0;
    uint4 u = *(const uint4*)&xin[base];
    float4 g0 = *(const float4*)&gt[i0];
    float4 g1 = *(const float4*)&gt[i0 + 4];
    float4 b0 = *(const float4*)&bt[i0];
    float4 b1 = *(const float4*)&bt[i0 + 4];
    unsigned w[4] = {u.x, u.y, u.z, u.w};
    float gv[8] = {g0.x, g0.y, g0.z, g0.w, g1.x, g1.y, g1.z, g1.w};
    float bv[8] = {b0.x, b0.y, b0.z, b0.w, b1.x, b1.y, b1.z, b1.w};
    unsigned o[4];
#pragma unroll
    for (int j = 0; j < 4; ++j) {
        float lo = __uint_as_float(w[j] << 16);
        float hi = __uint_as_float(w[j] & 0xffff0000u);
        lo = (lo - m) * r * gv[2 * j] + bv[2 * j];
        hi = (hi - m) * r * gv[2 * j + 1] + bv[2 * j + 1];
        o[j] = (unsigned)f2bu(lo) | ((unsigned)f2bu(hi) << 16);
    }
    uint4 st4 = make_uint4(o[0], o[1], o[2], o[3]);
    *(uint4*)&out[base] = st4;
}

// ---------------- stride-1 conv body (device fn; shared by wrappers) --------
template <int CI, int CO_TOTAL, int CO_BLK, int EPI, int ROWS>
__device__ __forceinline__ void conv_body(char* pool,
                                          const bf16* __restrict__ in,
                                          const bf16* __restrict__ wpk,
                                          const float* __restrict__ bias,
                                          const void* __restrict__ res,
                                          void* __restrict__ out,
                                          const bf16* __restrict__ zpage,
                                          float2* __restrict__ spart_out,
                                          int in_s0, int out_s0,
                                          int ng, int cg, int smp) {
    constexpr int CHUNKS = CI / 32;
    constexpr int MT = CO_BLK / 16;
    constexpr int NT = ROWS * 64;
    constexpr int HR = ROWS + 2;
    constexpr int IN_ITEMS = HR * 66 * 4;
    constexpr int IN_PAD = ((IN_ITEMS + 63) / 64) * 64;
    constexpr int IN_ITERS = (IN_PAD + NT - 1) / NT;
    constexpr int W_ITEMS = 9 * CO_BLK * 4;
    constexpr int W_ITERS = (W_ITEMS + NT - 1) / NT;

    short* s_in = (short*)pool;
    short* s_w = (short*)(pool + (size_t)IN_PAD * 16);
    float* rsum = (float*)(pool + (size_t)IN_PAD * 16 + 9 * CO_BLK * 64);
    float* rss = rsum + NT;

    const int tid = threadIdx.x;
    const int lane = tid & 63;
    const int wv = tid >> 6;
    const int quad = lane >> 4;
    const int n16 = lane & 15;
    const int co0 = cg * CO_BLK;
    const int y0 = ng * ROWS;

    const size_t in_base = (size_t)(in_s0 + smp) * 4096 * CI;

    int gin[IN_ITERS];
#pragma unroll
    for (int it = 0; it < IN_ITERS; ++it) {
        int i = it * NT + tid;
        int sub = i & 3;
        int x = (i >> 2) % 66;
        int row = i / 264;
        int y = y0 + row - 1;
        int xg = x - 1;
        bool ok = (i < IN_ITEMS) && (y >= 0) && (y < 64) && (xg >= 0) && (xg < 64);
        int grp = sub ^ (x & 3) ^ ((x >> 2) & 1);
        gin[it] = ok ? ((y * 64 + xg) * CI + grp * 8) : -1;
    }
    int gw[W_ITERS];
#pragma unroll
    for (int it = 0; it < W_ITERS; ++it) {
        int i = it * NT + tid;
        if (i < W_ITEMS) {
            int sub = i & 3;
            int co = (i >> 2) % CO_BLK;
            int tap = i / (CO_BLK * 4);
            int grp = sub ^ (co & 3) ^ ((co >> 2) & 1);
            gw[it] = (tap * CO_TOTAL + co0 + co) * CI + grp * 8;
        } else gw[it] = 0;
    }

    f32x4 acc[MT][4];
#pragma unroll
    for (int mt = 0; mt < MT; ++mt)
#pragma unroll
        for (int j = 0; j < 4; ++j) acc[mt][j] = (f32x4){0.f, 0.f, 0.f, 0.f};

    for (int chunk = 0; chunk < CHUNKS; ++chunk) {
        const int ci0 = chunk * 32;
        __syncthreads();
#pragma unroll
        for (int it = 0; it < IN_ITERS; ++it) {
            int i0 = it * NT + (tid & ~63);
            if (i0 < IN_PAD) {
                const bf16* gp = (gin[it] >= 0) ? (in + in_base + gin[it] + ci0) : zpage;
                gload16(gp, s_in + (size_t)i0 * 8);
            }
        }
#pragma unroll
        for (int it = 0; it < W_ITERS; ++it) {
            int i0 = it * NT + (tid & ~63);
            if (i0 < W_ITEMS) {
                const bf16* gp = wpk + gw[it] + ci0;
                gload16(gp, s_w + (size_t)i0 * 8);
            }
        }
        __syncthreads();

#pragma unroll
        for (int ky = 0; ky < 3; ++ky) {
#pragma unroll
            for (int kx = 0; kx < 3; ++kx) {
                const int tap = ky * 3 + kx;
                bf16x8 bfrag[4];
#pragma unroll
                for (int j = 0; j < 4; ++j) {
                    int x = j * 16 + n16 + kx;
                    int ps = quad ^ (x & 3) ^ ((x >> 2) & 1);
                    bfrag[j] = *(const bf16x8*)&s_in[((wv + ky) * 66 + x) * 32 + ps * 8];
                }
#pragma unroll
                for (int mt = 0; mt < MT; ++mt) {
                    int mrow = mt * 16 + n16;
                    int ps = quad ^ (mrow & 3) ^ ((mrow >> 2) & 1);
                    bf16x8 afrag = *(const bf16x8*)&s_w[(tap * CO_BLK + mrow) * 32 + ps * 8];
#pragma unroll
                    for (int j = 0; j < 4; ++j)
                        acc[mt][j] = __builtin_amdgcn_mfma_f32_16x16x32_bf16(afrag, bfrag[j], acc[mt][j], 0, 0, 0);
                }
            }
        }
    }

    const int osmp = out_s0 + smp;
    float lsum = 0.f, lss = 0.f;
#pragma unroll
    for (int j = 0; j < 4; ++j) {
        int pos = (y0 + wv) * 64 + j * 16 + n16;
#pragma unroll
        for (int mt = 0; mt < MT; ++mt) {
            int coutb = co0 + mt * 16 + quad * 4;
            float b0 = 0.f, b1 = 0.f, b2 = 0.f, b3 = 0.f;
            if constexpr (EPI != 1) {
                float4 bv = *(const float4*)&bias[coutb];
                b0 = bv.x; b1 = bv.y; b2 = bv.z; b3 = bv.w;
            }
            float v0 = acc[mt][j][0] + b0;
            float v1 = acc[mt][j][1] + b1;
            float v2 = acc[mt][j][2] + b2;
            float v3 = acc[mt][j][3] + b3;
            if constexpr (EPI == 1 || EPI == 2 || EPI == 3) {
                if constexpr (EPI == 2) {
                    const float* xr = (const float*)res + (size_t)osmp * 131072 + (size_t)coutb * 4096 + pos;
                    v0 += xr[0]; v1 += xr[4096]; v2 += xr[8192]; v3 += xr[12288];
                    lsum += v0 + v1 + v2 + v3;
                    lss += v0 * v0 + v1 * v1 + v2 * v2 + v3 * v3;
                } else if constexpr (EPI == 3) {
                    v0 = gelu_new(v0); v1 = gelu_new(v1); v2 = gelu_new(v2); v3 = gelu_new(v3);
                }
                ushort4 st;
                st.x = f2bu(v0); st.y = f2bu(v1); st.z = f2bu(v2); st.w = f2bu(v3);
                *(ushort4*)&((bf16*)out)[((size_t)osmp * 4096 + pos) * CO_TOTAL + coutb] = st;
            } else {
                ushort4 rv = *(const ushort4*)&((const bf16*)res)[((size_t)osmp * 4096 + pos) * 32 + coutb];
                v0 += su2f(rv.x); v1 += su2f(rv.y); v2 += su2f(rv.z); v3 += su2f(rv.w);
                float* op = (float*)out + (size_t)osmp * 131072 + (size_t)coutb * 4096 + pos;
                op[0] = v0; op[4096] = v1; op[8192] = v2; op[12288] = v3;
            }
        }
    }

    if constexpr (EPI == 2) {
        rsum[tid] = lsum; rss[tid] = lss;
        __syncthreads();
        for (int off = NT / 2; off > 0; off >>= 1) {
            if (tid < off) { rsum[tid] += rsum[tid + off]; rss[tid] += rss[tid + off]; }
            __syncthreads();
        }
        if (tid == 0) spart_out[smp * 8 + ng] = make_float2(rsum[0], rss[0]);
    }
}

// ---------------- stride-1 conv wrapper kernel ----------------
template <int CI, int CO_TOTAL, int CO_BLK, int EPI, int ROWS = 8>
__global__ __launch_bounds__(ROWS * 64) void conv_lds(const bf16* __restrict__ in,
                                                      const bf16* __restrict__ wpk,
                                                      const float* __restrict__ bias,
                                                      const void* __restrict__ res,
                                                      void* __restrict__ out,
                                                      const bf16* __restrict__ zpage,
                                                      float2* __restrict__ spart_out,
                                                      int in_s0, int out_s0) {
    constexpr int NG = 64 / ROWS;
    constexpr int IN_PAD = ((((ROWS + 2) * 66 * 4) + 63) / 64) * 64;
    constexpr int POOL = IN_PAD * 16 + 9 * CO_BLK * 64 + (EPI == 2 ? ROWS * 64 * 8 : 0);
    __shared__ __align__(16) char pool[POOL];
    conv_body<CI, CO_TOTAL, CO_BLK, EPI, ROWS>(pool, in, wpk, bias, res, out, zpage,
                                               spart_out, in_s0, out_s0,
                                               blockIdx.x % NG, blockIdx.x / NG, blockIdx.y);
}

// ---------------- merged KQ (stride-2, CO=64, 8-wave) + V (stride-1) --------
// grid (10, 128), 512 threads. bx<2: KQ role (ng=bx); bx>=2: V role (ng=bx-2).
// Both roles share one LDS pool (union); all threads of a block take the same
// branch (blockIdx-based), so __syncthreads stays uniform.
__global__ __launch_bounds__(512) void conv_kqv(const bf16* __restrict__ xn,
                                                const bf16* __restrict__ wpk_kq,
                                                const bf16* __restrict__ wpk_v,
                                                bf16* __restrict__ KQ,
                                                bf16* __restrict__ Vb,
                                                const bf16* __restrict__ zpage) {
    __shared__ __align__(16) char pool[61440];
    const int bx = blockIdx.x;
    const int smp = blockIdx.y;
    if (bx >= 2) {
        conv_body<32, 32, 32, 1, 8>(pool, xn, wpk_v, nullptr, nullptr, Vb, zpage,
                                    nullptr, 0, 0, bx - 2, 0, smp);
        return;
    }
    // ---- KQ role: stride-2 conv, CO_TOTAL=CO_BLK=64, 8 waves, NG=2 ----
    constexpr int PAD = 40;                 // 32 + 8 pad (bank-conflict break)
    short* s_w = (short*)pool;              // 9*64*40*2 = 46080 B <= pool
    const int tid = threadIdx.x;
    const int lane = tid & 63;
    const int wv = tid >> 6;
    const int quad = lane >> 4;
    const int n16 = lane & 15;
    const int ng = bx;

    f32x4 acc[4][4];
#pragma unroll
    for (int mt = 0; mt < 4; ++mt)
#pragma unroll
        for (int j = 0; j < 4; ++j) acc[mt][j] = (f32x4){0.f, 0.f, 0.f, 0.f};

    const size_t in_base = (size_t)smp * 4096 * 32;

    for (int idx = tid; idx < 4608; idx += 512) {
        int e = idx * 4;
        int tap = e / 2048;
        int rem = e - tap * 2048;
        int col = rem >> 5;
        int k = rem & 31;
        const ushort4 src = *(const ushort4*)&wpk_kq[((size_t)tap * 64 + col) * 32 + k];
        *(ushort4*)&s_w[(tap * 64 + col) * PAD + k] = src;
    }
    __syncthreads();

#pragma unroll
    for (int ky = 0; ky < 3; ++ky) {
#pragma unroll
        for (int kx = 0; kx < 3; ++kx) {
            const int tap = ky * 3 + kx;
            bf16x8 bfrag[4];
#pragma unroll
            for (int j = 0; j < 4; ++j) {
                int tile = ng * 32 + wv * 4 + j;
                int yo = tile >> 1;
                int xo = (tile & 1) * 16;
                int xi = (xo + n16) * 2 + kx - 1;
                int yi = yo * 2 + ky - 1;
                bool valid = (xi >= 0) && (xi < 64) && (yi >= 0) && (yi < 64);
                uint4 u;
                if (valid)
                    u = *(const uint4*)&xn[in_base + ((size_t)yi * 64 + xi) * 32 + quad * 8];
                else
                    u = make_uint4(0u, 0u, 0u, 0u);
                __builtin_memcpy(&bfrag[j], &u, 16);
            }
#pragma unroll
            for (int mt = 0; mt < 4; ++mt) {
                bf16x8 afrag = *(const bf16x8*)&s_w[(tap * 64 + mt * 16 + n16) * PAD + quad * 8];
#pragma unroll
                for (int j = 0; j < 4; ++j)
                    acc[mt][j] = __builtin_amdgcn_mfma_f32_16x16x32_bf16(afrag, bfrag[j], acc[mt][j], 0, 0, 0);
            }
        }
    }

#pragma unroll
    for (int j = 0; j < 4; ++j) {
        int tile = ng * 32 + wv * 4 + j;
        int yo = tile >> 1;
        int xo = (tile & 1) * 16;
        int pos = yo * 32 + xo + n16;
#pragma unroll
        for (int mt = 0; mt < 4; ++mt) {
            int coutb = mt * 16 + quad * 4;
            ushort4 st;
            st.x = f2bu(acc[mt][j][0]); st.y = f2bu(acc[mt][j][1]);
            st.z = f2bu(acc[mt][j][2]); st.w = f2bu(acc[mt][j][3]);
            *(ushort4*)&KQ[((size_t)smp * 1024 + pos) * 64 + coutb] = st;
        }
    }
}

// ---------------- attention scores + softmax : fused MFMA ----------------
// KQ merged layout: [bt][1024 p][64 c]; K = c 0..31, Q = c 32..63.
__global__ __launch_bounds__(256) void attn_scores_mfma(const bf16* __restrict__ KQ,
                                                        bf16* __restrict__ att) {
    __shared__ float red[4][32][33];
    __shared__ float sc[32][33];
    const int tid = threadIdx.x;
    const int lane = tid & 63;
    const int wv = tid >> 6;
    const int quad = lane >> 4;
    const int n16 = lane & 15;
    const int h = blockIdx.x & 7;
    const int b = blockIdx.x >> 3;
    const size_t base = (size_t)b * 32 * 65536 + (size_t)h * 4;

    f32x4 acc[2][2];
#pragma unroll
    for (int mt = 0; mt < 2; ++mt)
#pragma unroll
        for (int nt = 0; nt < 2; ++nt) acc[mt][nt] = (f32x4){0.f, 0.f, 0.f, 0.f};

    for (int kc = 0; kc < 32; ++kc) {
        const int p0 = wv * 256 + kc * 8 + quad * 2;
        bf16x8 afrag[2], bfrag[2];
#pragma unroll
        for (int mt = 0; mt < 2; ++mt) {
            const bf16* qp = &KQ[base + 32 + (size_t)(mt * 16 + n16) * 65536 + (size_t)p0 * 64];
            uint2 lo = *(const uint2*)qp;
            uint2 hi = *(const uint2*)(qp + 64);
            uint4 u = make_uint4(lo.x, lo.y, hi.x, hi.y);
            __builtin_memcpy(&afrag[mt], &u, 16);
        }
#pragma unroll
        for (int nt = 0; nt < 2; ++nt) {
            const bf16* kp = &KQ[base + (size_t)(nt * 16 + n16) * 65536 + (size_t)p0 * 64];
            uint2 lo = *(const uint2*)kp;
            uint2 hi = *(const uint2*)(kp + 64);
            uint4 u = make_uint4(lo.x, lo.y, hi.x, hi.y);
            __builtin_memcpy(&bfrag[nt], &u, 16);
        }
#pragma unroll
        for (int mt = 0; mt < 2; ++mt)
#pragma unroll
            for (int nt = 0; nt < 2; ++nt)
                acc[mt][nt] = __builtin_amdgcn_mfma_f32_16x16x32_bf16(afrag[mt], bfrag[nt], acc[mt][nt], 0, 0, 0);
    }
#pragma unroll
    for (int mt = 0; mt < 2; ++mt)
#pragma unroll
        for (int nt = 0; nt < 2; ++nt)
#pragma unroll
            for (int r = 0; r < 4; ++r)
                red[wv][mt * 16 + quad * 4 + r][nt * 16 + n16] = acc[mt][nt][r];
    __syncthreads();
    for (int i = tid; i < 1024; i += 256) {
        int t = i >> 5, s = i & 31;
        sc[t][s] = (red[0][t][s] + red[1][t][s] + red[2][t][s] + red[3][t][s]) * (1.0f / 64.0f);
    }
    __syncthreads();
    if (tid < 32) {
        float mx = -1e30f;
        for (int s2 = 0; s2 < 32; ++s2) mx = fmaxf(mx, sc[tid][s2]);
        float sum = 0.f;
        for (int s2 = 0; s2 < 32; ++s2) sum += expf(sc[tid][s2] - mx);
        float inv = 1.f / sum;
        bf16* arow = &att[((size_t)blockIdx.x * 32 + tid) * 32];
        for (int s2 = 0; s2 < 32; ++s2) arow[s2] = f2b(expf(sc[tid][s2] - mx) * inv);
    }
}

// ---------------- y = att @ v : MFMA with fused in-LDS V transpose ----------
__global__ __launch_bounds__(256) void attn_apply_mfma(const bf16* __restrict__ att,
                                                       const bf16* __restrict__ V,
                                                       bf16* __restrict__ Y) {
    __shared__ short vlds[512 * 40];
    __shared__ short ylds[32 * 512];
    const int tid = threadIdx.x;
    const int lane = tid & 63;
    const int wv = tid >> 6;
    const int quad = lane >> 4;
    const int n16 = lane & 15;
    const int pb = blockIdx.x;
    const int b = blockIdx.y;

    for (int l = 0; l < 8; ++l) {
        int u = l * 256 + tid;
        int s = u >> 6;
        int col8 = (u & 63) * 8;
        uint4 v = *(const uint4*)&V[(((size_t)(b * 32 + s) * 4096 + pb * 16) * 32) + col8];
        unsigned short us[8];
        __builtin_memcpy(us, &v, 16);
#pragma unroll
        for (int j = 0; j < 8; ++j) {
            int idx = col8 + j;
            int p = idx >> 5, c = idx & 31;
            int row = ((c >> 2) * 16 + p) * 4 + (c & 3);
            vlds[row * 40 + s] = (short)us[j];
        }
    }
    __syncthreads();

    const int e = wv * 16 + n16;
    const int p = e >> 2, cl = e & 3;
    for (int h = 0; h < 8; ++h) {
        bf16x8 bfrag = *(const bf16x8*)&vlds[(h * 64 + e) * 40 + quad * 8];
        const int c = h * 4 + cl;
#pragma unroll
        for (int mt = 0; mt < 2; ++mt) {
            bf16x8 afrag = *(const bf16x8*)&att[((size_t)(b * 8 + h) * 32 + mt * 16 + n16) * 32 + quad * 8];
            f32x4 d = __builtin_amdgcn_mfma_f32_16x16x32_bf16(afrag, bfrag,
                                                              (f32x4){0.f, 0.f, 0.f, 0.f}, 0, 0, 0);
#pragma unroll
            for (int r = 0; r < 4; ++r) {
                int t = mt * 16 + quad * 4 + r;
                ylds[t * 512 + p * 32 + c] = (short)f2bu(d[r]);
            }
        }
    }
    __syncthreads();

    for (int l = 0; l < 8; ++l) {
        int u = l * 256 + tid;
        int t = u >> 6;
        int col8 = (u & 63) * 8;
        *(uint4*)&Y[(((size_t)(b * 32 + t) * 4096 + pb * 16) * 32) + col8] =
            *(const uint4*)&ylds[t * 512 + col8];
    }
}

extern "C" void kernel_launch(void* const* d_in, const int* in_sizes, int n_in,
                              void* d_out, int out_size, void* d_ws, size_t ws_size,
                              hipStream_t stream) {
    const float* x   = (const float*)d_in[0];
    const float* n1g = (const float*)d_in[1];
    const float* n1b = (const float*)d_in[2];
    const float* n2g = (const float*)d_in[3];
    const float* n2b = (const float*)d_in[4];
    const float* Wk  = (const float*)d_in[5];
    const float* Wq  = (const float*)d_in[6];
    const float* Wv  = (const float*)d_in[7];
    const float* Wo  = (const float*)d_in[8];
    const float* bo  = (const float*)d_in[9];
    const float* Wm1 = (const float*)d_in[10];
    const float* bm1 = (const float*)d_in[11];
    const float* Wm2 = (const float*)d_in[12];
    const float* bm2 = (const float*)d_in[13];

    char* ws = (char*)d_ws;
    const size_t A_OFF = 0;
    const size_t B_OFF = 33554432;
    const size_t D_OFF = 67108864;
    const size_t E_OFF = 67239936;
    const size_t F_OFF = 67461120;
    const size_t C_OFF = 68519936;

    bf16*  xn   = (bf16*)(ws + A_OFF);
    bf16*  Yb   = (bf16*)(ws + A_OFF);
    bf16*  xn2  = (bf16*)(ws + A_OFF);
    bf16*  Vb   = (bf16*)(ws + B_OFF);
    bf16*  X1   = (bf16*)(ws + B_OFF);
    bf16*  attbf = (bf16*)(ws + D_OFF);
    bf16*  wpk_kq = (bf16*)(ws + E_OFF);            // 9*64*32*2 = 36864 B
    bf16*  wpk_v  = (bf16*)(ws + E_OFF + 36864);
    bf16*  wpk_o  = (bf16*)(ws + E_OFF + 55296);
    bf16*  wpk_m1 = (bf16*)(ws + E_OFF + 73728);
    bf16*  wpk_m2 = (bf16*)(ws + E_OFF + 147456);
    float* g2t  = (float*)(ws + F_OFF);
    float* b2t  = (float*)(ws + F_OFF + 524288);
    float2* spart = (float2*)(ws + F_OFF + 1048576);
    bf16*  zpg  = (bf16*)(ws + F_OFF + 1057792);    // 256 B zero page
    bf16*  KQb  = (bf16*)(ws + C_OFF);              // [128][1024][64] bf16 = 16 MB
    bf16*  Hb   = (bf16*)(ws + C_OFF);

    const size_t HB_PER_SAMPLE = 1048576;
    int chunk = 128;
    if (ws_size < C_OFF + 128 * HB_PER_SAMPLE) {
        size_t avail = (ws_size > C_OFF) ? (ws_size - C_OFF) : HB_PER_SAMPLE;
        chunk = (int)(avail / HB_PER_SAMPLE);
        if (chunk < 1) chunk = 1;
        if (chunk > 128) chunk = 128;
    }

    // 0. merged setup
    setup_all<<<1457, 256, 0, stream>>>(Wk, Wq, Wv, Wo, Wm1, Wm2, n2g, n2b,
                                        wpk_kq, wpk_v, wpk_o, wpk_m1, wpk_m2,
                                        g2t, b2t, (float*)zpg);
    // 1. LN1 stats + normalize/transpose (stats inlined from spart)
    ln_part_f32<<<dim3(8, 128), 256, 0, stream>>>(x, spart);
    ln1_norm_t<<<dim3(32, 128), 256, 0, stream>>>(x, n1g, n1b, spart, xn);
    // 2. merged KQ (stride-2) + V (stride-1) conv — independent, one launch
    conv_kqv<<<dim3(10, 128), 512, 0, stream>>>(xn, wpk_kq, wpk_v, KQb, Vb, zpg);
    // 3. attention scores + softmax
    attn_scores_mfma<<<32, 256, 0, stream>>>(KQb, attbf);
    // 4. y = att @ v
    attn_apply_mfma<<<dim3(256, 4), 256, 0, stream>>>(attbf, Vb, Yb);
    // 5. Wo conv + bias + residual -> X1; fused LN2 partial stats -> spart
    conv_lds<32, 32, 32, 2, 8><<<dim3(8, 128), 512, 0, stream>>>(Yb, wpk_o, bo, x, X1, zpg, spart, 0, 0);
    // 6. LN2 normalize (stats inlined from spart)
    ln2_norm<<<dim3(64, 128), 256, 0, stream>>>(X1, g2t, b2t, spart, xn2);
    // 7-8. mixer
    for (int s0 = 0; s0 < 128; s0 += chunk) {
        int n = (128 - s0 < chunk) ? (128 - s0) : chunk;
        conv_lds<32, 128, 64, 3, 8><<<dim3(16, n), 512, 0, stream>>>(xn2, wpk_m1, bm1, nullptr, Hb, zpg, nullptr, s0, 0);
        conv_lds<128, 32, 32, 4, 8><<<dim3(8, n), 512, 0, stream>>>(Hb, wpk_m2, bm2, X1, (float*)d_out, zpg, nullptr, 0, s0);
    }
}

// Round 13
// 405.978 us; speedup vs baseline: 1.2063x; 1.1095x over previous
//
#include <hip/hip_runtime.h>
#include <hip/hip_bf16.h>

using bf16 = __hip_bfloat16;
typedef short bf16x8 __attribute__((ext_vector_type(8)));
typedef float f32x4 __attribute__((ext_vector_type(4)));

#define AS1 __attribute__((address_space(1)))
#define AS3 __attribute__((address_space(3)))

__device__ inline float b2f(bf16 h) { return __bfloat162float(h); }
__device__ inline bf16 f2b(float f) { return __float2bfloat16(f); }
__device__ inline unsigned short f2bu(float f) {
    bf16 h = __float2bfloat16(f);
    unsigned short u;
    __builtin_memcpy(&u, &h, 2);
    return u;
}
__device__ inline float su2f(unsigned short u) {
    unsigned v = ((unsigned)u) << 16;
    return __uint_as_float(v);
}
// async global->LDS, 16B per lane, LDS dest = wave-uniform base + lane*16
__device__ inline void gload16(const bf16* gp, short* lp) {
    __builtin_amdgcn_global_load_lds((const AS1 void*)gp, (AS3 void*)lp, 16, 0, 0);
}
__device__ inline float fast_rcp(float a) {
#if __has_builtin(__builtin_amdgcn_rcpf)
    return __builtin_amdgcn_rcpf(a);
#else
    return 1.0f / a;
#endif
}
// NewGELU: x * rcp(1 + exp2(-c2*(x+a*x^3))), c2 = 2*sqrt(2/pi)*log2(e).
__device__ inline float gelu_new(float x) {
    float x3 = x * x * x;
    float z = -2.3022082f * __builtin_fmaf(0.044715f, x3, x);
    float e = exp2f(z);
    return x * fast_rcp(1.0f + e);
}
// inline LN stats from 8 partials
__device__ inline float2 ln_stats(const float2* spart, int sample) {
    float s = 0.f, ss = 0.f;
#pragma unroll
    for (int j = 0; j < 8; ++j) {
        float2 v = spart[sample * 8 + j];
        s += v.x; ss += v.y;
    }
    float m = s * (1.f / 131072.f);
    float var = ss * (1.f / 131072.f) - m * m;
    return make_float2(m, rsqrtf(var + 1e-5f));
}
// XCD-aware bijective block remap (T1): groups contiguous logical work per XCD
// so same-sample blocks (sharing halo rows / xn) hit the same L2. Identity
// when grid not divisible by 8.
__device__ inline int xcd_swz_id() {
    int bid = blockIdx.y * gridDim.x + blockIdx.x;
    int nwg = gridDim.x * gridDim.y;
    if ((nwg & 7) == 0) return (bid & 7) * (nwg >> 3) + (bid >> 3);
    return bid;
}

// ---------------- merged setup: weight packs + g/b transpose + zero page ----
__device__ inline void pack_one(const float* w, bf16* wpk, int i,
                                int CO, int CI, int CO_TOTAL, int co_off) {
    int tap = i % 9;
    int ci = (i / 9) % CI;
    int co = i / (9 * CI);
    wpk[((size_t)tap * CO_TOTAL + co_off + co) * CI + ci] = f2b(w[i]);
}
__global__ __launch_bounds__(256) void setup_all(const float* __restrict__ Wk,
                                                 const float* __restrict__ Wq,
                                                 const float* __restrict__ Wv,
                                                 const float* __restrict__ Wo,
                                                 const float* __restrict__ Wm1,
                                                 const float* __restrict__ Wm2,
                                                 const float* __restrict__ n2g,
                                                 const float* __restrict__ n2b,
                                                 bf16* __restrict__ wpk_kq,
                                                 bf16* __restrict__ wpk_v,
                                                 bf16* __restrict__ wpk_o,
                                                 bf16* __restrict__ wpk_m1,
                                                 bf16* __restrict__ wpk_m2,
                                                 float* __restrict__ gt,
                                                 float* __restrict__ bt,
                                                 float* __restrict__ zp) {
    int i = blockIdx.x * 256 + threadIdx.x;
    if (i < 9216)            pack_one(Wk, wpk_kq, i, 32, 32, 64, 0);
    else if (i < 18432)      pack_one(Wq, wpk_kq, i - 9216, 32, 32, 64, 32);
    else if (i < 27648)      pack_one(Wv, wpk_v, i - 18432, 32, 32, 32, 0);
    else if (i < 36864)      pack_one(Wo, wpk_o, i - 27648, 32, 32, 32, 0);
    else if (i < 73728)      pack_one(Wm1, wpk_m1, i - 36864, 128, 32, 128, 0);
    else if (i < 110592)     pack_one(Wm2, wpk_m2, i - 73728, 32, 128, 32, 0);
    else if (i < 110656)     zp[i - 110592] = 0.f;
    else if (i < 372800) {
        int j = i - 110656;
        int sel = j >> 17;
        int o = j & 131071;
        int p = o >> 5, c = o & 31;
        int src = c * 4096 + p;
        if (sel == 0) gt[o] = n2g[src];
        else          bt[o] = n2b[src];
    }
}

// ---------------- LN partial reduce (f32): grid (8, 128) ----------------
__global__ __launch_bounds__(256) void ln_part_f32(const float* __restrict__ xin,
                                                   float2* __restrict__ spart) {
    const int tid = threadIdx.x;
    const int sample = blockIdx.y, seg = blockIdx.x;
    const size_t base = (size_t)sample * 131072 + seg * 16384;
    float sum = 0.f, ss = 0.f;
    const float4* p = (const float4*)(xin + base);
    for (int l = 0; l < 16; ++l) {
        float4 v = p[l * 256 + tid];
        sum += v.x + v.y + v.z + v.w;
        ss += v.x * v.x + v.y * v.y + v.z * v.z + v.w * v.w;
    }
    __shared__ float rs[256], rs2[256];
    rs[tid] = sum; rs2[tid] = ss;
    __syncthreads();
    for (int off = 128; off > 0; off >>= 1) {
        if (tid < off) { rs[tid] += rs[tid + off]; rs2[tid] += rs2[tid + off]; }
        __syncthreads();
    }
    if (tid == 0) spart[sample * 8 + seg] = make_float2(rs[0], rs2[0]);
}

// ---------------- LN1 normalize + NCHW->NHWC transpose (inline stats) -------
__global__ __launch_bounds__(256) void ln1_norm_t(const float* __restrict__ x,
                                                  const float* __restrict__ g,
                                                  const float* __restrict__ bb,
                                                  const float2* __restrict__ spart,
                                                  bf16* __restrict__ out) {
    __shared__ float tile[32][129];
    const int tid = threadIdx.x;
    const int sample = blockIdx.y;
    const int p0 = blockIdx.x * 128;
    float2 st = ln_stats(spart, sample);
    const float m = st.x, r = st.y;
    const size_t xb = (size_t)sample * 131072;
    for (int k = 0; k < 16; ++k) {
        int idx = k * 256 + tid;
        int c = idx >> 7, p = idx & 127;
        int gi = c * 4096 + p0 + p;
        float v = x[xb + gi];
        tile[c][p] = (v - m) * r * g[gi] + bb[gi];
    }
    __syncthreads();
    for (int k = 0; k < 8; ++k) {
        int idx = k * 256 + tid;
        int p = idx >> 4, c2 = (idx & 15) * 2;
        unsigned lo = (unsigned)f2bu(tile[c2][p]);
        unsigned hi = (unsigned)f2bu(tile[c2 + 1][p]);
        *(unsigned*)&out[xb + (size_t)(p0 + p) * 32 + c2] = lo | (hi << 16);
    }
}

// ---------------- LN2 normalize, NHWC linear (inline stats) ----------------
__global__ __launch_bounds__(256) void ln2_norm(const bf16* __restrict__ xin,
                                                const float* __restrict__ gt,
                                                const float* __restrict__ bt,
                                                const float2* __restrict__ spart,
                                                bf16* __restrict__ out) {
    const int tid = threadIdx.x;
    const int sample = blockIdx.y;
    float2 st = ln_stats(spart, sample);
    const float m = st.x, r = st.y;
    int i0 = (blockIdx.x * 256 + tid) * 8;
    const size_t base = (size_t)sample * 131072 + i0;
    uint4 u = *(const uint4*)&xin[base];
    float4 g0 = *(const float4*)&gt[i0];
    float4 g1 = *(const float4*)&gt[i0 + 4];
    float4 b0 = *(const float4*)&bt[i0];
    float4 b1 = *(const float4*)&bt[i0 + 4];
    unsigned w[4] = {u.x, u.y, u.z, u.w};
    float gv[8] = {g0.x, g0.y, g0.z, g0.w, g1.x, g1.y, g1.z, g1.w};
    float bv[8] = {b0.x, b0.y, b0.z, b0.w, b1.x, b1.y, b1.z, b1.w};
    unsigned o[4];
#pragma unroll
    for (int j = 0; j < 4; ++j) {
        float lo = __uint_as_float(w[j] << 16);
        float hi = __uint_as_float(w[j] & 0xffff0000u);
        lo = (lo - m) * r * gv[2 * j] + bv[2 * j];
        hi = (hi - m) * r * gv[2 * j + 1] + bv[2 * j + 1];
        o[j] = (unsigned)f2bu(lo) | ((unsigned)f2bu(hi) << 16);
    }
    uint4 st4 = make_uint4(o[0], o[1], o[2], o[3]);
    *(uint4*)&out[base] = st4;
}

// ---------------- stride-1 conv body (device fn; shared by wrappers) --------
template <int CI, int CO_TOTAL, int CO_BLK, int EPI, int ROWS>
__device__ __forceinline__ void conv_body(char* pool,
                                          const bf16* __restrict__ in,
                                          const bf16* __restrict__ wpk,
                                          const float* __restrict__ bias,
                                          const void* __restrict__ res,
                                          void* __restrict__ out,
                                          const bf16* __restrict__ zpage,
                                          float2* __restrict__ spart_out,
                                          int in_s0, int out_s0,
                                          int ng, int cg, int smp) {
    constexpr int CHUNKS = CI / 32;
    constexpr int MT = CO_BLK / 16;
    constexpr int NT = ROWS * 64;
    constexpr int HR = ROWS + 2;
    constexpr int IN_ITEMS = HR * 66 * 4;
    constexpr int IN_PAD = ((IN_ITEMS + 63) / 64) * 64;
    constexpr int IN_ITERS = (IN_PAD + NT - 1) / NT;
    constexpr int W_ITEMS = 9 * CO_BLK * 4;
    constexpr int W_ITERS = (W_ITEMS + NT - 1) / NT;

    short* s_in = (short*)pool;
    short* s_w = (short*)(pool + (size_t)IN_PAD * 16);
    float* rsum = (float*)(pool + (size_t)IN_PAD * 16 + 9 * CO_BLK * 64);
    float* rss = rsum + NT;

    const int tid = threadIdx.x;
    const int lane = tid & 63;
    const int wv = tid >> 6;
    const int quad = lane >> 4;
    const int n16 = lane & 15;
    const int co0 = cg * CO_BLK;
    const int y0 = ng * ROWS;

    const size_t in_base = (size_t)(in_s0 + smp) * 4096 * CI;

    int gin[IN_ITERS];
#pragma unroll
    for (int it = 0; it < IN_ITERS; ++it) {
        int i = it * NT + tid;
        int sub = i & 3;
        int x = (i >> 2) % 66;
        int row = i / 264;
        int y = y0 + row - 1;
        int xg = x - 1;
        bool ok = (i < IN_ITEMS) && (y >= 0) && (y < 64) && (xg >= 0) && (xg < 64);
        int grp = sub ^ (x & 3) ^ ((x >> 2) & 1);
        gin[it] = ok ? ((y * 64 + xg) * CI + grp * 8) : -1;
    }
    int gw[W_ITERS];
#pragma unroll
    for (int it = 0; it < W_ITERS; ++it) {
        int i = it * NT + tid;
        if (i < W_ITEMS) {
            int sub = i & 3;
            int co = (i >> 2) % CO_BLK;
            int tap = i / (CO_BLK * 4);
            int grp = sub ^ (co & 3) ^ ((co >> 2) & 1);
            gw[it] = (tap * CO_TOTAL + co0 + co) * CI + grp * 8;
        } else gw[it] = 0;
    }

    f32x4 acc[MT][4];
#pragma unroll
    for (int mt = 0; mt < MT; ++mt)
#pragma unroll
        for (int j = 0; j < 4; ++j) acc[mt][j] = (f32x4){0.f, 0.f, 0.f, 0.f};

    for (int chunk = 0; chunk < CHUNKS; ++chunk) {
        const int ci0 = chunk * 32;
        __syncthreads();
#pragma unroll
        for (int it = 0; it < IN_ITERS; ++it) {
            int i0 = it * NT + (tid & ~63);
            if (i0 < IN_PAD) {
                const bf16* gp = (gin[it] >= 0) ? (in + in_base + gin[it] + ci0) : zpage;
                gload16(gp, s_in + (size_t)i0 * 8);
            }
        }
#pragma unroll
        for (int it = 0; it < W_ITERS; ++it) {
            int i0 = it * NT + (tid & ~63);
            if (i0 < W_ITEMS) {
                const bf16* gp = wpk + gw[it] + ci0;
                gload16(gp, s_w + (size_t)i0 * 8);
            }
        }
        __syncthreads();

#pragma unroll
        for (int ky = 0; ky < 3; ++ky) {
#pragma unroll
            for (int kx = 0; kx < 3; ++kx) {
                const int tap = ky * 3 + kx;
                bf16x8 bfrag[4];
#pragma unroll
                for (int j = 0; j < 4; ++j) {
                    int x = j * 16 + n16 + kx;
                    int ps = quad ^ (x & 3) ^ ((x >> 2) & 1);
                    bfrag[j] = *(const bf16x8*)&s_in[((wv + ky) * 66 + x) * 32 + ps * 8];
                }
#pragma unroll
                for (int mt = 0; mt < MT; ++mt) {
                    int mrow = mt * 16 + n16;
                    int ps = quad ^ (mrow & 3) ^ ((mrow >> 2) & 1);
                    bf16x8 afrag = *(const bf16x8*)&s_w[(tap * CO_BLK + mrow) * 32 + ps * 8];
#pragma unroll
                    for (int j = 0; j < 4; ++j)
                        acc[mt][j] = __builtin_amdgcn_mfma_f32_16x16x32_bf16(afrag, bfrag[j], acc[mt][j], 0, 0, 0);
                }
            }
        }
    }

    const int osmp = out_s0 + smp;
    float lsum = 0.f, lss = 0.f;
#pragma unroll
    for (int j = 0; j < 4; ++j) {
        int pos = (y0 + wv) * 64 + j * 16 + n16;
#pragma unroll
        for (int mt = 0; mt < MT; ++mt) {
            int coutb = co0 + mt * 16 + quad * 4;
            float b0 = 0.f, b1 = 0.f, b2 = 0.f, b3 = 0.f;
            if constexpr (EPI != 1) {
                float4 bv = *(const float4*)&bias[coutb];
                b0 = bv.x; b1 = bv.y; b2 = bv.z; b3 = bv.w;
            }
            float v0 = acc[mt][j][0] + b0;
            float v1 = acc[mt][j][1] + b1;
            float v2 = acc[mt][j][2] + b2;
            float v3 = acc[mt][j][3] + b3;
            if constexpr (EPI == 1 || EPI == 2 || EPI == 3) {
                if constexpr (EPI == 2) {
                    const float* xr = (const float*)res + (size_t)osmp * 131072 + (size_t)coutb * 4096 + pos;
                    v0 += xr[0]; v1 += xr[4096]; v2 += xr[8192]; v3 += xr[12288];
                    lsum += v0 + v1 + v2 + v3;
                    lss += v0 * v0 + v1 * v1 + v2 * v2 + v3 * v3;
                } else if constexpr (EPI == 3) {
                    v0 = gelu_new(v0); v1 = gelu_new(v1); v2 = gelu_new(v2); v3 = gelu_new(v3);
                }
                ushort4 st;
                st.x = f2bu(v0); st.y = f2bu(v1); st.z = f2bu(v2); st.w = f2bu(v3);
                *(ushort4*)&((bf16*)out)[((size_t)osmp * 4096 + pos) * CO_TOTAL + coutb] = st;
            } else {
                ushort4 rv = *(const ushort4*)&((const bf16*)res)[((size_t)osmp * 4096 + pos) * 32 + coutb];
                v0 += su2f(rv.x); v1 += su2f(rv.y); v2 += su2f(rv.z); v3 += su2f(rv.w);
                float* op = (float*)out + (size_t)osmp * 131072 + (size_t)coutb * 4096 + pos;
                op[0] = v0; op[4096] = v1; op[8192] = v2; op[12288] = v3;
            }
        }
    }

    if constexpr (EPI == 2) {
        rsum[tid] = lsum; rss[tid] = lss;
        __syncthreads();
        for (int off = NT / 2; off > 0; off >>= 1) {
            if (tid < off) { rsum[tid] += rsum[tid + off]; rss[tid] += rss[tid + off]; }
            __syncthreads();
        }
        if (tid == 0) spart_out[smp * 8 + ng] = make_float2(rsum[0], rss[0]);
    }
}

// ---------------- stride-1 conv wrapper kernel (XCD-swizzled) ----------------
template <int CI, int CO_TOTAL, int CO_BLK, int EPI, int ROWS = 8>
__global__ __launch_bounds__(ROWS * 64) void conv_lds(const bf16* __restrict__ in,
                                                      const bf16* __restrict__ wpk,
                                                      const float* __restrict__ bias,
                                                      const void* __restrict__ res,
                                                      void* __restrict__ out,
                                                      const bf16* __restrict__ zpage,
                                                      float2* __restrict__ spart_out,
                                                      int in_s0, int out_s0) {
    constexpr int NG = 64 / ROWS;
    constexpr int IN_PAD = ((((ROWS + 2) * 66 * 4) + 63) / 64) * 64;
    constexpr int POOL = IN_PAD * 16 + 9 * CO_BLK * 64 + (EPI == 2 ? ROWS * 64 * 8 : 0);
    __shared__ __align__(16) char pool[POOL];
    int l = xcd_swz_id();
    int bx = l % gridDim.x;
    int smp = l / gridDim.x;
    conv_body<CI, CO_TOTAL, CO_BLK, EPI, ROWS>(pool, in, wpk, bias, res, out, zpage,
                                               spart_out, in_s0, out_s0,
                                               bx % NG, bx / NG, smp);
}

// ---------------- merged KQ (stride-2, CO=64, 8-wave) + V (stride-1) --------
// XCD-swizzled: all 10 roles of a sample land on one XCD (xn L2 reuse).
__global__ __launch_bounds__(512) void conv_kqv(const bf16* __restrict__ xn,
                                                const bf16* __restrict__ wpk_kq,
                                                const bf16* __restrict__ wpk_v,
                                                bf16* __restrict__ KQ,
                                                bf16* __restrict__ Vb,
                                                const bf16* __restrict__ zpage) {
    __shared__ __align__(16) char pool[61440];
    int l = xcd_swz_id();
    const int bx = l % gridDim.x;
    const int smp = l / gridDim.x;
    if (bx >= 2) {
        conv_body<32, 32, 32, 1, 8>(pool, xn, wpk_v, nullptr, nullptr, Vb, zpage,
                                    nullptr, 0, 0, bx - 2, 0, smp);
        return;
    }
    // ---- KQ role: stride-2 conv, CO_TOTAL=CO_BLK=64, 8 waves, NG=2 ----
    constexpr int PAD = 40;
    short* s_w = (short*)pool;              // 9*64*40*2 = 46080 B <= pool
    const int tid = threadIdx.x;
    const int lane = tid & 63;
    const int wv = tid >> 6;
    const int quad = lane >> 4;
    const int n16 = lane & 15;
    const int ng = bx;

    f32x4 acc[4][4];
#pragma unroll
    for (int mt = 0; mt < 4; ++mt)
#pragma unroll
        for (int j = 0; j < 4; ++j) acc[mt][j] = (f32x4){0.f, 0.f, 0.f, 0.f};

    const size_t in_base = (size_t)smp * 4096 * 32;

    for (int idx = tid; idx < 4608; idx += 512) {
        int e = idx * 4;
        int tap = e / 2048;
        int rem = e - tap * 2048;
        int col = rem >> 5;
        int k = rem & 31;
        const ushort4 src = *(const ushort4*)&wpk_kq[((size_t)tap * 64 + col) * 32 + k];
        *(ushort4*)&s_w[(tap * 64 + col) * PAD + k] = src;
    }
    __syncthreads();

#pragma unroll
    for (int ky = 0; ky < 3; ++ky) {
#pragma unroll
        for (int kx = 0; kx < 3; ++kx) {
            const int tap = ky * 3 + kx;
            bf16x8 bfrag[4];
#pragma unroll
            for (int j = 0; j < 4; ++j) {
                int tile = ng * 32 + wv * 4 + j;
                int yo = tile >> 1;
                int xo = (tile & 1) * 16;
                int xi = (xo + n16) * 2 + kx - 1;
                int yi = yo * 2 + ky - 1;
                bool valid = (xi >= 0) && (xi < 64) && (yi >= 0) && (yi < 64);
                uint4 u;
                if (valid)
                    u = *(const uint4*)&xn[in_base + ((size_t)yi * 64 + xi) * 32 + quad * 8];
                else
                    u = make_uint4(0u, 0u, 0u, 0u);
                __builtin_memcpy(&bfrag[j], &u, 16);
            }
#pragma unroll
            for (int mt = 0; mt < 4; ++mt) {
                bf16x8 afrag = *(const bf16x8*)&s_w[(tap * 64 + mt * 16 + n16) * PAD + quad * 8];
#pragma unroll
                for (int j = 0; j < 4; ++j)
                    acc[mt][j] = __builtin_amdgcn_mfma_f32_16x16x32_bf16(afrag, bfrag[j], acc[mt][j], 0, 0, 0);
            }
        }
    }

#pragma unroll
    for (int j = 0; j < 4; ++j) {
        int tile = ng * 32 + wv * 4 + j;
        int yo = tile >> 1;
        int xo = (tile & 1) * 16;
        int pos = yo * 32 + xo + n16;
#pragma unroll
        for (int mt = 0; mt < 4; ++mt) {
            int coutb = mt * 16 + quad * 4;
            ushort4 st;
            st.x = f2bu(acc[mt][j][0]); st.y = f2bu(acc[mt][j][1]);
            st.z = f2bu(acc[mt][j][2]); st.w = f2bu(acc[mt][j][3]);
            *(ushort4*)&KQ[((size_t)smp * 1024 + pos) * 64 + coutb] = st;
        }
    }
}

// ---------------- attention scores, p-split partials: grid (8 seg, 32 bh) ---
// Splits the 1024-position reduction over 8 blocks (256 blocks total vs 32)
// so the QK^T phase uses the whole chip; f32 partials to scpart.
__global__ __launch_bounds__(256) void attn_scores_part(const bf16* __restrict__ KQ,
                                                        float* __restrict__ scpart) {
    __shared__ float red[4][32][33];
    const int tid = threadIdx.x;
    const int lane = tid & 63;
    const int wv = tid >> 6;
    const int quad = lane >> 4;
    const int n16 = lane & 15;
    const int seg = blockIdx.x;
    const int bh = blockIdx.y;
    const int h = bh & 7;
    const int b = bh >> 3;
    const size_t base = (size_t)b * 32 * 65536 + (size_t)h * 4;

    f32x4 acc[2][2];
#pragma unroll
    for (int mt = 0; mt < 2; ++mt)
#pragma unroll
        for (int nt = 0; nt < 2; ++nt) acc[mt][nt] = (f32x4){0.f, 0.f, 0.f, 0.f};

    for (int kc = 0; kc < 4; ++kc) {
        const int p0 = seg * 128 + wv * 32 + kc * 8 + quad * 2;
        bf16x8 afrag[2], bfrag[2];
#pragma unroll
        for (int mt = 0; mt < 2; ++mt) {
            const bf16* qp = &KQ[base + 32 + (size_t)(mt * 16 + n16) * 65536 + (size_t)p0 * 64];
            uint2 lo = *(const uint2*)qp;
            uint2 hi = *(const uint2*)(qp + 64);
            uint4 u = make_uint4(lo.x, lo.y, hi.x, hi.y);
            __builtin_memcpy(&afrag[mt], &u, 16);
        }
#pragma unroll
        for (int nt = 0; nt < 2; ++nt) {
            const bf16* kp = &KQ[base + (size_t)(nt * 16 + n16) * 65536 + (size_t)p0 * 64];
            uint2 lo = *(const uint2*)kp;
            uint2 hi = *(const uint2*)(kp + 64);
            uint4 u = make_uint4(lo.x, lo.y, hi.x, hi.y);
            __builtin_memcpy(&bfrag[nt], &u, 16);
        }
#pragma unroll
        for (int mt = 0; mt < 2; ++mt)
#pragma unroll
            for (int nt = 0; nt < 2; ++nt)
                acc[mt][nt] = __builtin_amdgcn_mfma_f32_16x16x32_bf16(afrag[mt], bfrag[nt], acc[mt][nt], 0, 0, 0);
    }
#pragma unroll
    for (int mt = 0; mt < 2; ++mt)
#pragma unroll
        for (int nt = 0; nt < 2; ++nt)
#pragma unroll
            for (int r = 0; r < 4; ++r)
                red[wv][mt * 16 + quad * 4 + r][nt * 16 + n16] = acc[mt][nt][r];
    __syncthreads();
    float* dst = scpart + ((size_t)bh * 8 + seg) * 1024;
    for (int i = tid; i < 1024; i += 256) {
        int t = i >> 5, s = i & 31;
        dst[i] = red[0][t][s] + red[1][t][s] + red[2][t][s] + red[3][t][s];
    }
}

// ---------------- combine partials + softmax -> att bf16 : grid 32 ----------
__global__ __launch_bounds__(256) void attn_soft(const float* __restrict__ scpart,
                                                 bf16* __restrict__ att) {
    __shared__ float sc[32][33];
    const int tid = threadIdx.x;
    const int bh = blockIdx.x;
    const float* src = scpart + (size_t)bh * 8192;
    for (int i = tid; i < 1024; i += 256) {
        float v = 0.f;
#pragma unroll
        for (int g = 0; g < 8; ++g) v += src[g * 1024 + i];
        sc[i >> 5][i & 31] = v * (1.0f / 64.0f);
    }
    __syncthreads();
    if (tid < 32) {
        float mx = -1e30f;
        for (int s2 = 0; s2 < 32; ++s2) mx = fmaxf(mx, sc[tid][s2]);
        float sum = 0.f;
        for (int s2 = 0; s2 < 32; ++s2) sum += expf(sc[tid][s2] - mx);
        float inv = 1.f / sum;
        bf16* arow = &att[((size_t)bh * 32 + tid) * 32];
        for (int s2 = 0; s2 < 32; ++s2) arow[s2] = f2b(expf(sc[tid][s2] - mx) * inv);
    }
}

// ---------------- y = att @ v : MFMA with fused in-LDS V transpose ----------
__global__ __launch_bounds__(256) void attn_apply_mfma(const bf16* __restrict__ att,
                                                       const bf16* __restrict__ V,
                                                       bf16* __restrict__ Y) {
    __shared__ short vlds[512 * 40];
    __shared__ short ylds[32 * 512];
    const int tid = threadIdx.x;
    const int lane = tid & 63;
    const int wv = tid >> 6;
    const int quad = lane >> 4;
    const int n16 = lane & 15;
    const int pb = blockIdx.x;
    const int b = blockIdx.y;

    for (int l = 0; l < 8; ++l) {
        int u = l * 256 + tid;
        int s = u >> 6;
        int col8 = (u & 63) * 8;
        uint4 v = *(const uint4*)&V[(((size_t)(b * 32 + s) * 4096 + pb * 16) * 32) + col8];
        unsigned short us[8];
        __builtin_memcpy(us, &v, 16);
#pragma unroll
        for (int j = 0; j < 8; ++j) {
            int idx = col8 + j;
            int p = idx >> 5, c = idx & 31;
            int row = ((c >> 2) * 16 + p) * 4 + (c & 3);
            vlds[row * 40 + s] = (short)us[j];
        }
    }
    __syncthreads();

    const int e = wv * 16 + n16;
    const int p = e >> 2, cl = e & 3;
    for (int h = 0; h < 8; ++h) {
        bf16x8 bfrag = *(const bf16x8*)&vlds[(h * 64 + e) * 40 + quad * 8];
        const int c = h * 4 + cl;
#pragma unroll
        for (int mt = 0; mt < 2; ++mt) {
            bf16x8 afrag = *(const bf16x8*)&att[((size_t)(b * 8 + h) * 32 + mt * 16 + n16) * 32 + quad * 8];
            f32x4 d = __builtin_amdgcn_mfma_f32_16x16x32_bf16(afrag, bfrag,
                                                              (f32x4){0.f, 0.f, 0.f, 0.f}, 0, 0, 0);
#pragma unroll
            for (int r = 0; r < 4; ++r) {
                int t = mt * 16 + quad * 4 + r;
                ylds[t * 512 + p * 32 + c] = (short)f2bu(d[r]);
            }
        }
    }
    __syncthreads();

    for (int l = 0; l < 8; ++l) {
        int u = l * 256 + tid;
        int t = u >> 6;
        int col8 = (u & 63) * 8;
        *(uint4*)&Y[(((size_t)(b * 32 + t) * 4096 + pb * 16) * 32) + col8] =
            *(const uint4*)&ylds[t * 512 + col8];
    }
}

extern "C" void kernel_launch(void* const* d_in, const int* in_sizes, int n_in,
                              void* d_out, int out_size, void* d_ws, size_t ws_size,
                              hipStream_t stream) {
    const float* x   = (const float*)d_in[0];
    const float* n1g = (const float*)d_in[1];
    const float* n1b = (const float*)d_in[2];
    const float* n2g = (const float*)d_in[3];
    const float* n2b = (const float*)d_in[4];
    const float* Wk  = (const float*)d_in[5];
    const float* Wq  = (const float*)d_in[6];
    const float* Wv  = (const float*)d_in[7];
    const float* Wo  = (const float*)d_in[8];
    const float* bo  = (const float*)d_in[9];
    const float* Wm1 = (const float*)d_in[10];
    const float* bm1 = (const float*)d_in[11];
    const float* Wm2 = (const float*)d_in[12];
    const float* bm2 = (const float*)d_in[13];

    char* ws = (char*)d_ws;
    const size_t A_OFF = 0;
    const size_t B_OFF = 33554432;
    const size_t D_OFF = 67108864;
    const size_t E_OFF = 67239936;
    const size_t F_OFF = 67461120;
    const size_t C_OFF = 68519936;

    bf16*  xn   = (bf16*)(ws + A_OFF);
    bf16*  Yb   = (bf16*)(ws + A_OFF);
    bf16*  xn2  = (bf16*)(ws + A_OFF);
    bf16*  Vb   = (bf16*)(ws + B_OFF);
    bf16*  X1   = (bf16*)(ws + B_OFF);
    bf16*  attbf = (bf16*)(ws + D_OFF);
    bf16*  wpk_kq = (bf16*)(ws + E_OFF);
    bf16*  wpk_v  = (bf16*)(ws + E_OFF + 36864);
    bf16*  wpk_o  = (bf16*)(ws + E_OFF + 55296);
    bf16*  wpk_m1 = (bf16*)(ws + E_OFF + 73728);
    bf16*  wpk_m2 = (bf16*)(ws + E_OFF + 147456);
    float* g2t  = (float*)(ws + F_OFF);
    float* b2t  = (float*)(ws + F_OFF + 524288);
    float2* spart = (float2*)(ws + F_OFF + 1048576);
    bf16*  zpg  = (bf16*)(ws + F_OFF + 1057792);
    bf16*  KQb  = (bf16*)(ws + C_OFF);              // 16 MB
    float* scpart = (float*)(ws + C_OFF + 16777216); // 1 MB, dead before mixer
    bf16*  Hb   = (bf16*)(ws + C_OFF);

    const size_t HB_PER_SAMPLE = 1048576;
    int chunk = 128;
    if (ws_size < C_OFF + 128 * HB_PER_SAMPLE) {
        size_t avail = (ws_size > C_OFF) ? (ws_size - C_OFF) : HB_PER_SAMPLE;
        chunk = (int)(avail / HB_PER_SAMPLE);
        if (chunk < 1) chunk = 1;
        if (chunk > 128) chunk = 128;
    }

    // 0. merged setup
    setup_all<<<1457, 256, 0, stream>>>(Wk, Wq, Wv, Wo, Wm1, Wm2, n2g, n2b,
                                        wpk_kq, wpk_v, wpk_o, wpk_m1, wpk_m2,
                                        g2t, b2t, (float*)zpg);
    // 1. LN1 stats + normalize/transpose
    ln_part_f32<<<dim3(8, 128), 256, 0, stream>>>(x, spart);
    ln1_norm_t<<<dim3(32, 128), 256, 0, stream>>>(x, n1g, n1b, spart, xn);
    // 2. merged KQ (stride-2) + V (stride-1) conv (XCD-swizzled)
    conv_kqv<<<dim3(10, 128), 512, 0, stream>>>(xn, wpk_kq, wpk_v, KQb, Vb, zpg);
    // 3. attention scores: p-split partials then combine+softmax
    attn_scores_part<<<dim3(8, 32), 256, 0, stream>>>(KQb, scpart);
    attn_soft<<<32, 256, 0, stream>>>(scpart, attbf);
    // 4. y = att @ v
    attn_apply_mfma<<<dim3(256, 4), 256, 0, stream>>>(attbf, Vb, Yb);
    // 5. Wo conv + bias + residual -> X1; fused LN2 partial stats
    conv_lds<32, 32, 32, 2, 8><<<dim3(8, 128), 512, 0, stream>>>(Yb, wpk_o, bo, x, X1, zpg, spart, 0, 0);
    // 6. LN2 normalize
    ln2_norm<<<dim3(64, 128), 256, 0, stream>>>(X1, g2t, b2t, spart, xn2);
    // 7-8. mixer (XCD-swizzled)
    for (int s0 = 0; s0 < 128; s0 += chunk) {
        int n = (128 - s0 < chunk) ? (128 - s0) : chunk;
        conv_lds<32, 128, 64, 3, 8><<<dim3(16, n), 512, 0, stream>>>(xn2, wpk_m1, bm1, nullptr, Hb, zpg, nullptr, s0, 0);
        conv_lds<128, 32, 32, 4, 8><<<dim3(8, n), 512, 0, stream>>>(Hb, wpk_m2, bm2, X1, (float*)d_out, zpg, nullptr, 0, s0);
    }
}

// Round 14
// 403.221 us; speedup vs baseline: 1.2145x; 1.0068x over previous
//
#include <hip/hip_runtime.h>
#include <hip/hip_bf16.h>

using bf16 = __hip_bfloat16;
typedef short bf16x8 __attribute__((ext_vector_type(8)));
typedef float f32x4 __attribute__((ext_vector_type(4)));

#define AS1 __attribute__((address_space(1)))
#define AS3 __attribute__((address_space(3)))

__device__ inline float b2f(bf16 h) { return __bfloat162float(h); }
__device__ inline bf16 f2b(float f) { return __float2bfloat16(f); }
__device__ inline unsigned short f2bu(float f) {
    bf16 h = __float2bfloat16(f);
    unsigned short u;
    __builtin_memcpy(&u, &h, 2);
    return u;
}
__device__ inline float su2f(unsigned short u) {
    unsigned v = ((unsigned)u) << 16;
    return __uint_as_float(v);
}
// async global->LDS, 16B per lane, LDS dest = wave-uniform base + lane*16
__device__ inline void gload16(const bf16* gp, short* lp) {
    __builtin_amdgcn_global_load_lds((const AS1 void*)gp, (AS3 void*)lp, 16, 0, 0);
}
__device__ inline float fast_rcp(float a) {
#if __has_builtin(__builtin_amdgcn_rcpf)
    return __builtin_amdgcn_rcpf(a);
#else
    return 1.0f / a;
#endif
}
__device__ inline float fast_exp2(float z) {
#if __has_builtin(__builtin_amdgcn_exp2f)
    return __builtin_amdgcn_exp2f(z);      // single v_exp_f32 (HW exp IS exp2)
#else
    return __expf(0.69314718056f * z);     // native exp fallback
#endif
}
// NewGELU: x * rcp(1 + exp2(-c2*(x+a*x^3))), c2 = 2*sqrt(2/pi)*log2(e).
__device__ inline float gelu_new(float x) {
    float x3 = x * x * x;
    float z = -2.3022082f * __builtin_fmaf(0.044715f, x3, x);
    float e = fast_exp2(z);
    return x * fast_rcp(1.0f + e);
}
// inline LN stats from 8 partials
__device__ inline float2 ln_stats(const float2* spart, int sample) {
    float s = 0.f, ss = 0.f;
#pragma unroll
    for (int j = 0; j < 8; ++j) {
        float2 v = spart[sample * 8 + j];
        s += v.x; ss += v.y;
    }
    float m = s * (1.f / 131072.f);
    float var = ss * (1.f / 131072.f) - m * m;
    return make_float2(m, rsqrtf(var + 1e-5f));
}
// XCD-aware bijective block remap (T1). Identity when grid not /8.
__device__ inline int xcd_swz_id() {
    int bid = blockIdx.y * gridDim.x + blockIdx.x;
    int nwg = gridDim.x * gridDim.y;
    if ((nwg & 7) == 0) return (bid & 7) * (nwg >> 3) + (bid >> 3);
    return bid;
}

// ---------------- merged setup: weight packs + g/b transpose + zero page ----
__device__ inline void pack_one(const float* w, bf16* wpk, int i,
                                int CO, int CI, int CO_TOTAL, int co_off) {
    int tap = i % 9;
    int ci = (i / 9) % CI;
    int co = i / (9 * CI);
    wpk[((size_t)tap * CO_TOTAL + co_off + co) * CI + ci] = f2b(w[i]);
}
__global__ __launch_bounds__(256) void setup_all(const float* __restrict__ Wk,
                                                 const float* __restrict__ Wq,
                                                 const float* __restrict__ Wv,
                                                 const float* __restrict__ Wo,
                                                 const float* __restrict__ Wm1,
                                                 const float* __restrict__ Wm2,
                                                 const float* __restrict__ n2g,
                                                 const float* __restrict__ n2b,
                                                 bf16* __restrict__ wpk_kq,
                                                 bf16* __restrict__ wpk_v,
                                                 bf16* __restrict__ wpk_o,
                                                 bf16* __restrict__ wpk_m1,
                                                 bf16* __restrict__ wpk_m2,
                                                 float* __restrict__ gt,
                                                 float* __restrict__ bt,
                                                 float* __restrict__ zp) {
    int i = blockIdx.x * 256 + threadIdx.x;
    if (i < 9216)            pack_one(Wk, wpk_kq, i, 32, 32, 64, 0);
    else if (i < 18432)      pack_one(Wq, wpk_kq, i - 9216, 32, 32, 64, 32);
    else if (i < 27648)      pack_one(Wv, wpk_v, i - 18432, 32, 32, 32, 0);
    else if (i < 36864)      pack_one(Wo, wpk_o, i - 27648, 32, 32, 32, 0);
    else if (i < 73728)      pack_one(Wm1, wpk_m1, i - 36864, 128, 32, 128, 0);
    else if (i < 110592)     pack_one(Wm2, wpk_m2, i - 73728, 32, 128, 32, 0);
    else if (i < 110656)     zp[i - 110592] = 0.f;
    else if (i < 372800) {
        int j = i - 110656;
        int sel = j >> 17;
        int o = j & 131071;
        int p = o >> 5, c = o & 31;
        int src = c * 4096 + p;
        if (sel == 0) gt[o] = n2g[src];
        else          bt[o] = n2b[src];
    }
}

// ---------------- LN partial reduce (f32): grid (8, 128) ----------------
__global__ __launch_bounds__(256) void ln_part_f32(const float* __restrict__ xin,
                                                   float2* __restrict__ spart) {
    const int tid = threadIdx.x;
    const int sample = blockIdx.y, seg = blockIdx.x;
    const size_t base = (size_t)sample * 131072 + seg * 16384;
    float sum = 0.f, ss = 0.f;
    const float4* p = (const float4*)(xin + base);
    for (int l = 0; l < 16; ++l) {
        float4 v = p[l * 256 + tid];
        sum += v.x + v.y + v.z + v.w;
        ss += v.x * v.x + v.y * v.y + v.z * v.z + v.w * v.w;
    }
    __shared__ float rs[256], rs2[256];
    rs[tid] = sum; rs2[tid] = ss;
    __syncthreads();
    for (int off = 128; off > 0; off >>= 1) {
        if (tid < off) { rs[tid] += rs[tid + off]; rs2[tid] += rs2[tid + off]; }
        __syncthreads();
    }
    if (tid == 0) spart[sample * 8 + seg] = make_float2(rs[0], rs2[0]);
}

// ---------------- LN1 normalize + NCHW->NHWC transpose (inline stats) -------
__global__ __launch_bounds__(256) void ln1_norm_t(const float* __restrict__ x,
                                                  const float* __restrict__ g,
                                                  const float* __restrict__ bb,
                                                  const float2* __restrict__ spart,
                                                  bf16* __restrict__ out) {
    __shared__ float tile[32][129];
    const int tid = threadIdx.x;
    const int sample = blockIdx.y;
    const int p0 = blockIdx.x * 128;
    float2 st = ln_stats(spart, sample);
    const float m = st.x, r = st.y;
    const size_t xb = (size_t)sample * 131072;
    for (int k = 0; k < 16; ++k) {
        int idx = k * 256 + tid;
        int c = idx >> 7, p = idx & 127;
        int gi = c * 4096 + p0 + p;
        float v = x[xb + gi];
        tile[c][p] = (v - m) * r * g[gi] + bb[gi];
    }
    __syncthreads();
    for (int k = 0; k < 8; ++k) {
        int idx = k * 256 + tid;
        int p = idx >> 4, c2 = (idx & 15) * 2;
        unsigned lo = (unsigned)f2bu(tile[c2][p]);
        unsigned hi = (unsigned)f2bu(tile[c2 + 1][p]);
        *(unsigned*)&out[xb + (size_t)(p0 + p) * 32 + c2] = lo | (hi << 16);
    }
}

// ---------------- LN2 normalize, NHWC linear (inline stats) ----------------
__global__ __launch_bounds__(256) void ln2_norm(const bf16* __restrict__ xin,
                                                const float* __restrict__ gt,
                                                const float* __restrict__ bt,
                                                const float2* __restrict__ spart,
                                                bf16* __restrict__ out) {
    const int tid = threadIdx.x;
    const int sample = blockIdx.y;
    float2 st = ln_stats(spart, sample);
    const float m = st.x, r = st.y;
    int i0 = (blockIdx.x * 256 + tid) * 8;
    const size_t base = (size_t)sample * 131072 + i0;
    uint4 u = *(const uint4*)&xin[base];
    float4 g0 = *(const float4*)&gt[i0];
    float4 g1 = *(const float4*)&gt[i0 + 4];
    float4 b0 = *(const float4*)&bt[i0];
    float4 b1 = *(const float4*)&bt[i0 + 4];
    unsigned w[4] = {u.x, u.y, u.z, u.w};
    float gv[8] = {g0.x, g0.y, g0.z, g0.w, g1.x, g1.y, g1.z, g1.w};
    float bv[8] = {b0.x, b0.y, b0.z, b0.w, b1.x, b1.y, b1.z, b1.w};
    unsigned o[4];
#pragma unroll
    for (int j = 0; j < 4; ++j) {
        float lo = __uint_as_float(w[j] << 16);
        float hi = __uint_as_float(w[j] & 0xffff0000u);
        lo = (lo - m) * r * gv[2 * j] + bv[2 * j];
        hi = (hi - m) * r * gv[2 * j + 1] + bv[2 * j + 1];
        o[j] = (unsigned)f2bu(lo) | ((unsigned)f2bu(hi) << 16);
    }
    uint4 st4 = make_uint4(o[0], o[1], o[2], o[3]);
    *(uint4*)&out[base] = st4;
}

// ---------------- stride-1 conv body (device fn; shared by wrappers) --------
template <int CI, int CO_TOTAL, int CO_BLK, int EPI, int ROWS>
__device__ __forceinline__ void conv_body(char* pool,
                                          const bf16* __restrict__ in,
                                          const bf16* __restrict__ wpk,
                                          const float* __restrict__ bias,
                                          const void* __restrict__ res,
                                          void* __restrict__ out,
                                          const bf16* __restrict__ zpage,
                                          float2* __restrict__ spart_out,
                                          int in_s0, int out_s0,
                                          int ng, int cg, int smp) {
    constexpr int CHUNKS = CI / 32;
    constexpr int MT = CO_BLK / 16;
    constexpr int NT = ROWS * 64;
    constexpr int HR = ROWS + 2;
    constexpr int IN_ITEMS = HR * 66 * 4;
    constexpr int IN_PAD = ((IN_ITEMS + 63) / 64) * 64;
    constexpr int IN_ITERS = (IN_PAD + NT - 1) / NT;
    constexpr int W_ITEMS = 9 * CO_BLK * 4;
    constexpr int W_ITERS = (W_ITEMS + NT - 1) / NT;

    short* s_in = (short*)pool;
    short* s_w = (short*)(pool + (size_t)IN_PAD * 16);
    float* rsum = (float*)(pool + (size_t)IN_PAD * 16 + 9 * CO_BLK * 64);
    float* rss = rsum + NT;

    const int tid = threadIdx.x;
    const int lane = tid & 63;
    const int wv = tid >> 6;
    const int quad = lane >> 4;
    const int n16 = lane & 15;
    const int co0 = cg * CO_BLK;
    const int y0 = ng * ROWS;

    const size_t in_base = (size_t)(in_s0 + smp) * 4096 * CI;

    int gin[IN_ITERS];
#pragma unroll
    for (int it = 0; it < IN_ITERS; ++it) {
        int i = it * NT + tid;
        int sub = i & 3;
        int x = (i >> 2) % 66;
        int row = i / 264;
        int y = y0 + row - 1;
        int xg = x - 1;
        bool ok = (i < IN_ITEMS) && (y >= 0) && (y < 64) && (xg >= 0) && (xg < 64);
        int grp = sub ^ (x & 3) ^ ((x >> 2) & 1);
        gin[it] = ok ? ((y * 64 + xg) * CI + grp * 8) : -1;
    }
    int gw[W_ITERS];
#pragma unroll
    for (int it = 0; it < W_ITERS; ++it) {
        int i = it * NT + tid;
        if (i < W_ITEMS) {
            int sub = i & 3;
            int co = (i >> 2) % CO_BLK;
            int tap = i / (CO_BLK * 4);
            int grp = sub ^ (co & 3) ^ ((co >> 2) & 1);
            gw[it] = (tap * CO_TOTAL + co0 + co) * CI + grp * 8;
        } else gw[it] = 0;
    }

    f32x4 acc[MT][4];
#pragma unroll
    for (int mt = 0; mt < MT; ++mt)
#pragma unroll
        for (int j = 0; j < 4; ++j) acc[mt][j] = (f32x4){0.f, 0.f, 0.f, 0.f};

    for (int chunk = 0; chunk < CHUNKS; ++chunk) {
        const int ci0 = chunk * 32;
        __syncthreads();
#pragma unroll
        for (int it = 0; it < IN_ITERS; ++it) {
            int i0 = it * NT + (tid & ~63);
            if (i0 < IN_PAD) {
                const bf16* gp = (gin[it] >= 0) ? (in + in_base + gin[it] + ci0) : zpage;
                gload16(gp, s_in + (size_t)i0 * 8);
            }
        }
#pragma unroll
        for (int it = 0; it < W_ITERS; ++it) {
            int i0 = it * NT + (tid & ~63);
            if (i0 < W_ITEMS) {
                const bf16* gp = wpk + gw[it] + ci0;
                gload16(gp, s_w + (size_t)i0 * 8);
            }
        }
        __syncthreads();

#pragma unroll
        for (int ky = 0; ky < 3; ++ky) {
#pragma unroll
            for (int kx = 0; kx < 3; ++kx) {
                const int tap = ky * 3 + kx;
                bf16x8 bfrag[4];
#pragma unroll
                for (int j = 0; j < 4; ++j) {
                    int x = j * 16 + n16 + kx;
                    int ps = quad ^ (x & 3) ^ ((x >> 2) & 1);
                    bfrag[j] = *(const bf16x8*)&s_in[((wv + ky) * 66 + x) * 32 + ps * 8];
                }
#pragma unroll
                for (int mt = 0; mt < MT; ++mt) {
                    int mrow = mt * 16 + n16;
                    int ps = quad ^ (mrow & 3) ^ ((mrow >> 2) & 1);
                    bf16x8 afrag = *(const bf16x8*)&s_w[(tap * CO_BLK + mrow) * 32 + ps * 8];
#pragma unroll
                    for (int j = 0; j < 4; ++j)
                        acc[mt][j] = __builtin_amdgcn_mfma_f32_16x16x32_bf16(afrag, bfrag[j], acc[mt][j], 0, 0, 0);
                }
            }
        }
    }

    const int osmp = out_s0 + smp;
    float lsum = 0.f, lss = 0.f;
#pragma unroll
    for (int j = 0; j < 4; ++j) {
        int pos = (y0 + wv) * 64 + j * 16 + n16;
#pragma unroll
        for (int mt = 0; mt < MT; ++mt) {
            int coutb = co0 + mt * 16 + quad * 4;
            float b0 = 0.f, b1 = 0.f, b2 = 0.f, b3 = 0.f;
            if constexpr (EPI != 1) {
                float4 bv = *(const float4*)&bias[coutb];
                b0 = bv.x; b1 = bv.y; b2 = bv.z; b3 = bv.w;
            }
            float v0 = acc[mt][j][0] + b0;
            float v1 = acc[mt][j][1] + b1;
            float v2 = acc[mt][j][2] + b2;
            float v3 = acc[mt][j][3] + b3;
            if constexpr (EPI == 1 || EPI == 2 || EPI == 3) {
                if constexpr (EPI == 2) {
                    const float* xr = (const float*)res + (size_t)osmp * 131072 + (size_t)coutb * 4096 + pos;
                    v0 += xr[0]; v1 += xr[4096]; v2 += xr[8192]; v3 += xr[12288];
                    lsum += v0 + v1 + v2 + v3;
                    lss += v0 * v0 + v1 * v1 + v2 * v2 + v3 * v3;
                } else if constexpr (EPI == 3) {
                    v0 = gelu_new(v0); v1 = gelu_new(v1); v2 = gelu_new(v2); v3 = gelu_new(v3);
                }
                ushort4 st;
                st.x = f2bu(v0); st.y = f2bu(v1); st.z = f2bu(v2); st.w = f2bu(v3);
                *(ushort4*)&((bf16*)out)[((size_t)osmp * 4096 + pos) * CO_TOTAL + coutb] = st;
            } else {
                ushort4 rv = *(const ushort4*)&((const bf16*)res)[((size_t)osmp * 4096 + pos) * 32 + coutb];
                v0 += su2f(rv.x); v1 += su2f(rv.y); v2 += su2f(rv.z); v3 += su2f(rv.w);
                float* op = (float*)out + (size_t)osmp * 131072 + (size_t)coutb * 4096 + pos;
                op[0] = v0; op[4096] = v1; op[8192] = v2; op[12288] = v3;
            }
        }
    }

    if constexpr (EPI == 2) {
        rsum[tid] = lsum; rss[tid] = lss;
        __syncthreads();
        for (int off = NT / 2; off > 0; off >>= 1) {
            if (tid < off) { rsum[tid] += rsum[tid + off]; rss[tid] += rss[tid + off]; }
            __syncthreads();
        }
        if (tid == 0) spart_out[smp * 8 + ng] = make_float2(rsum[0], rss[0]);
    }
}

// ---------------- stride-1 conv wrapper kernel (optional XCD swizzle) -------
// SWZ=false for L3-fit inputs (m1: swizzle measured -3.5us, WRITE +47MB).
template <int CI, int CO_TOTAL, int CO_BLK, int EPI, int ROWS = 8, bool SWZ = true>
__global__ __launch_bounds__(ROWS * 64) void conv_lds(const bf16* __restrict__ in,
                                                      const bf16* __restrict__ wpk,
                                                      const float* __restrict__ bias,
                                                      const void* __restrict__ res,
                                                      void* __restrict__ out,
                                                      const bf16* __restrict__ zpage,
                                                      float2* __restrict__ spart_out,
                                                      int in_s0, int out_s0) {
    constexpr int NG = 64 / ROWS;
    constexpr int IN_PAD = ((((ROWS + 2) * 66 * 4) + 63) / 64) * 64;
    constexpr int POOL = IN_PAD * 16 + 9 * CO_BLK * 64 + (EPI == 2 ? ROWS * 64 * 8 : 0);
    __shared__ __align__(16) char pool[POOL];
    int bx, smp;
    if constexpr (SWZ) {
        int l = xcd_swz_id();
        bx = l % gridDim.x;
        smp = l / gridDim.x;
    } else {
        bx = blockIdx.x;
        smp = blockIdx.y;
    }
    conv_body<CI, CO_TOTAL, CO_BLK, EPI, ROWS>(pool, in, wpk, bias, res, out, zpage,
                                               spart_out, in_s0, out_s0,
                                               bx % NG, bx / NG, smp);
}

// ---------------- merged KQ (stride-2, CO=64, 8-wave) + V (stride-1) --------
__global__ __launch_bounds__(512) void conv_kqv(const bf16* __restrict__ xn,
                                                const bf16* __restrict__ wpk_kq,
                                                const bf16* __restrict__ wpk_v,
                                                bf16* __restrict__ KQ,
                                                bf16* __restrict__ Vb,
                                                const bf16* __restrict__ zpage) {
    __shared__ __align__(16) char pool[61440];
    int l = xcd_swz_id();
    const int bx = l % gridDim.x;
    const int smp = l / gridDim.x;
    if (bx >= 2) {
        conv_body<32, 32, 32, 1, 8>(pool, xn, wpk_v, nullptr, nullptr, Vb, zpage,
                                    nullptr, 0, 0, bx - 2, 0, smp);
        return;
    }
    // ---- KQ role: stride-2 conv, CO_TOTAL=CO_BLK=64, 8 waves, NG=2 ----
    constexpr int PAD = 40;
    short* s_w = (short*)pool;
    const int tid = threadIdx.x;
    const int lane = tid & 63;
    const int wv = tid >> 6;
    const int quad = lane >> 4;
    const int n16 = lane & 15;
    const int ng = bx;

    f32x4 acc[4][4];
#pragma unroll
    for (int mt = 0; mt < 4; ++mt)
#pragma unroll
        for (int j = 0; j < 4; ++j) acc[mt][j] = (f32x4){0.f, 0.f, 0.f, 0.f};

    const size_t in_base = (size_t)smp * 4096 * 32;

    for (int idx = tid; idx < 4608; idx += 512) {
        int e = idx * 4;
        int tap = e / 2048;
        int rem = e - tap * 2048;
        int col = rem >> 5;
        int k = rem & 31;
        const ushort4 src = *(const ushort4*)&wpk_kq[((size_t)tap * 64 + col) * 32 + k];
        *(ushort4*)&s_w[(tap * 64 + col) * PAD + k] = src;
    }
    __syncthreads();

#pragma unroll
    for (int ky = 0; ky < 3; ++ky) {
#pragma unroll
        for (int kx = 0; kx < 3; ++kx) {
            const int tap = ky * 3 + kx;
            bf16x8 bfrag[4];
#pragma unroll
            for (int j = 0; j < 4; ++j) {
                int tile = ng * 32 + wv * 4 + j;
                int yo = tile >> 1;
                int xo = (tile & 1) * 16;
                int xi = (xo + n16) * 2 + kx - 1;
                int yi = yo * 2 + ky - 1;
                bool valid = (xi >= 0) && (xi < 64) && (yi >= 0) && (yi < 64);
                uint4 u;
                if (valid)
                    u = *(const uint4*)&xn[in_base + ((size_t)yi * 64 + xi) * 32 + quad * 8];
                else
                    u = make_uint4(0u, 0u, 0u, 0u);
                __builtin_memcpy(&bfrag[j], &u, 16);
            }
#pragma unroll
            for (int mt = 0; mt < 4; ++mt) {
                bf16x8 afrag = *(const bf16x8*)&s_w[(tap * 64 + mt * 16 + n16) * PAD + quad * 8];
#pragma unroll
                for (int j = 0; j < 4; ++j)
                    acc[mt][j] = __builtin_amdgcn_mfma_f32_16x16x32_bf16(afrag, bfrag[j], acc[mt][j], 0, 0, 0);
            }
        }
    }

#pragma unroll
    for (int j = 0; j < 4; ++j) {
        int tile = ng * 32 + wv * 4 + j;
        int yo = tile >> 1;
        int xo = (tile & 1) * 16;
        int pos = yo * 32 + xo + n16;
#pragma unroll
        for (int mt = 0; mt < 4; ++mt) {
            int coutb = mt * 16 + quad * 4;
            ushort4 st;
            st.x = f2bu(acc[mt][j][0]); st.y = f2bu(acc[mt][j][1]);
            st.z = f2bu(acc[mt][j][2]); st.w = f2bu(acc[mt][j][3]);
            *(ushort4*)&KQ[((size_t)smp * 1024 + pos) * 64 + coutb] = st;
        }
    }
}

// ---------------- attention scores, p-split partials: grid (8 seg, 32 bh) ---
__global__ __launch_bounds__(256) void attn_scores_part(const bf16* __restrict__ KQ,
                                                        float* __restrict__ scpart) {
    __shared__ float red[4][32][33];
    const int tid = threadIdx.x;
    const int lane = tid & 63;
    const int wv = tid >> 6;
    const int quad = lane >> 4;
    const int n16 = lane & 15;
    const int seg = blockIdx.x;
    const int bh = blockIdx.y;
    const int h = bh & 7;
    const int b = bh >> 3;
    const size_t base = (size_t)b * 32 * 65536 + (size_t)h * 4;

    f32x4 acc[2][2];
#pragma unroll
    for (int mt = 0; mt < 2; ++mt)
#pragma unroll
        for (int nt = 0; nt < 2; ++nt) acc[mt][nt] = (f32x4){0.f, 0.f, 0.f, 0.f};

    for (int kc = 0; kc < 4; ++kc) {
        const int p0 = seg * 128 + wv * 32 + kc * 8 + quad * 2;
        bf16x8 afrag[2], bfrag[2];
#pragma unroll
        for (int mt = 0; mt < 2; ++mt) {
            const bf16* qp = &KQ[base + 32 + (size_t)(mt * 16 + n16) * 65536 + (size_t)p0 * 64];
            uint2 lo = *(const uint2*)qp;
            uint2 hi = *(const uint2*)(qp + 64);
            uint4 u = make_uint4(lo.x, lo.y, hi.x, hi.y);
            __builtin_memcpy(&afrag[mt], &u, 16);
        }
#pragma unroll
        for (int nt = 0; nt < 2; ++nt) {
            const bf16* kp = &KQ[base + (size_t)(nt * 16 + n16) * 65536 + (size_t)p0 * 64];
            uint2 lo = *(const uint2*)kp;
            uint2 hi = *(const uint2*)(kp + 64);
            uint4 u = make_uint4(lo.x, lo.y, hi.x, hi.y);
            __builtin_memcpy(&bfrag[nt], &u, 16);
        }
#pragma unroll
        for (int mt = 0; mt < 2; ++mt)
#pragma unroll
            for (int nt = 0; nt < 2; ++nt)
                acc[mt][nt] = __builtin_amdgcn_mfma_f32_16x16x32_bf16(afrag[mt], bfrag[nt], acc[mt][nt], 0, 0, 0);
    }
#pragma unroll
    for (int mt = 0; mt < 2; ++mt)
#pragma unroll
        for (int nt = 0; nt < 2; ++nt)
#pragma unroll
            for (int r = 0; r < 4; ++r)
                red[wv][mt * 16 + quad * 4 + r][nt * 16 + n16] = acc[mt][nt][r];
    __syncthreads();
    float* dst = scpart + ((size_t)bh * 8 + seg) * 1024;
    for (int i = tid; i < 1024; i += 256) {
        int t = i >> 5, s = i & 31;
        dst[i] = red[0][t][s] + red[1][t][s] + red[2][t][s] + red[3][t][s];
    }
}

// ---------------- combine partials + softmax -> att bf16 : grid 32 ----------
__global__ __launch_bounds__(256) void attn_soft(const float* __restrict__ scpart,
                                                 bf16* __restrict__ att) {
    __shared__ float sc[32][33];
    const int tid = threadIdx.x;
    const int bh = blockIdx.x;
    const float* src = scpart + (size_t)bh * 8192;
    for (int i = tid; i < 1024; i += 256) {
        float v = 0.f;
#pragma unroll
        for (int g = 0; g < 8; ++g) v += src[g * 1024 + i];
        sc[i >> 5][i & 31] = v * (1.0f / 64.0f);
    }
    __syncthreads();
    if (tid < 32) {
        float mx = -1e30f;
        for (int s2 = 0; s2 < 32; ++s2) mx = fmaxf(mx, sc[tid][s2]);
        float sum = 0.f;
        for (int s2 = 0; s2 < 32; ++s2) sum += expf(sc[tid][s2] - mx);
        float inv = 1.f / sum;
        bf16* arow = &att[((size_t)bh * 32 + tid) * 32];
        for (int s2 = 0; s2 < 32; ++s2) arow[s2] = f2b(expf(sc[tid][s2] - mx) * inv);
    }
}

// ---------------- y = att @ v : MFMA with fused in-LDS V transpose ----------
__global__ __launch_bounds__(256) void attn_apply_mfma(const bf16* __restrict__ att,
                                                       const bf16* __restrict__ V,
                                                       bf16* __restrict__ Y) {
    __shared__ short vlds[512 * 40];
    __shared__ short ylds[32 * 512];
    const int tid = threadIdx.x;
    const int lane = tid & 63;
    const int wv = tid >> 6;
    const int quad = lane >> 4;
    const int n16 = lane & 15;
    const int pb = blockIdx.x;
    const int b = blockIdx.y;

    for (int l = 0; l < 8; ++l) {
        int u = l * 256 + tid;
        int s = u >> 6;
        int col8 = (u & 63) * 8;
        uint4 v = *(const uint4*)&V[(((size_t)(b * 32 + s) * 4096 + pb * 16) * 32) + col8];
        unsigned short us[8];
        __builtin_memcpy(us, &v, 16);
#pragma unroll
        for (int j = 0; j < 8; ++j) {
            int idx = col8 + j;
            int p = idx >> 5, c = idx & 31;
            int row = ((c >> 2) * 16 + p) * 4 + (c & 3);
            vlds[row * 40 + s] = (short)us[j];
        }
    }
    __syncthreads();

    const int e = wv * 16 + n16;
    const int p = e >> 2, cl = e & 3;
    for (int h = 0; h < 8; ++h) {
        bf16x8 bfrag = *(const bf16x8*)&vlds[(h * 64 + e) * 40 + quad * 8];
        const int c = h * 4 + cl;
#pragma unroll
        for (int mt = 0; mt < 2; ++mt) {
            bf16x8 afrag = *(const bf16x8*)&att[((size_t)(b * 8 + h) * 32 + mt * 16 + n16) * 32 + quad * 8];
            f32x4 d = __builtin_amdgcn_mfma_f32_16x16x32_bf16(afrag, bfrag,
                                                              (f32x4){0.f, 0.f, 0.f, 0.f}, 0, 0, 0);
#pragma unroll
            for (int r = 0; r < 4; ++r) {
                int t = mt * 16 + quad * 4 + r;
                ylds[t * 512 + p * 32 + c] = (short)f2bu(d[r]);
            }
        }
    }
    __syncthreads();

    for (int l = 0; l < 8; ++l) {
        int u = l * 256 + tid;
        int t = u >> 6;
        int col8 = (u & 63) * 8;
        *(uint4*)&Y[(((size_t)(b * 32 + t) * 4096 + pb * 16) * 32) + col8] =
            *(const uint4*)&ylds[t * 512 + col8];
    }
}

extern "C" void kernel_launch(void* const* d_in, const int* in_sizes, int n_in,
                              void* d_out, int out_size, void* d_ws, size_t ws_size,
                              hipStream_t stream) {
    const float* x   = (const float*)d_in[0];
    const float* n1g = (const float*)d_in[1];
    const float* n1b = (const float*)d_in[2];
    const float* n2g = (const float*)d_in[3];
    const float* n2b = (const float*)d_in[4];
    const float* Wk  = (const float*)d_in[5];
    const float* Wq  = (const float*)d_in[6];
    const float* Wv  = (const float*)d_in[7];
    const float* Wo  = (const float*)d_in[8];
    const float* bo  = (const float*)d_in[9];
    const float* Wm1 = (const float*)d_in[10];
    const float* bm1 = (const float*)d_in[11];
    const float* Wm2 = (const float*)d_in[12];
    const float* bm2 = (const float*)d_in[13];

    char* ws = (char*)d_ws;
    const size_t A_OFF = 0;
    const size_t B_OFF = 33554432;
    const size_t D_OFF = 67108864;
    const size_t E_OFF = 67239936;
    const size_t F_OFF = 67461120;
    const size_t C_OFF = 68519936;

    bf16*  xn   = (bf16*)(ws + A_OFF);
    bf16*  Yb   = (bf16*)(ws + A_OFF);
    bf16*  xn2  = (bf16*)(ws + A_OFF);
    bf16*  Vb   = (bf16*)(ws + B_OFF);
    bf16*  X1   = (bf16*)(ws + B_OFF);
    bf16*  attbf = (bf16*)(ws + D_OFF);
    bf16*  wpk_kq = (bf16*)(ws + E_OFF);
    bf16*  wpk_v  = (bf16*)(ws + E_OFF + 36864);
    bf16*  wpk_o  = (bf16*)(ws + E_OFF + 55296);
    bf16*  wpk_m1 = (bf16*)(ws + E_OFF + 73728);
    bf16*  wpk_m2 = (bf16*)(ws + E_OFF + 147456);
    float* g2t  = (float*)(ws + F_OFF);
    float* b2t  = (float*)(ws + F_OFF + 524288);
    float2* spart = (float2*)(ws + F_OFF + 1048576);
    bf16*  zpg  = (bf16*)(ws + F_OFF + 1057792);
    bf16*  KQb  = (bf16*)(ws + C_OFF);              // 16 MB
    float* scpart = (float*)(ws + C_OFF + 16777216); // 1 MB, dead before mixer
    bf16*  Hb   = (bf16*)(ws + C_OFF);

    const size_t HB_PER_SAMPLE = 1048576;
    int chunk = 128;
    if (ws_size < C_OFF + 128 * HB_PER_SAMPLE) {
        size_t avail = (ws_size > C_OFF) ? (ws_size - C_OFF) : HB_PER_SAMPLE;
        chunk = (int)(avail / HB_PER_SAMPLE);
        if (chunk < 1) chunk = 1;
        if (chunk > 128) chunk = 128;
    }

    // 0. merged setup
    setup_all<<<1457, 256, 0, stream>>>(Wk, Wq, Wv, Wo, Wm1, Wm2, n2g, n2b,
                                        wpk_kq, wpk_v, wpk_o, wpk_m1, wpk_m2,
                                        g2t, b2t, (float*)zpg);
    // 1. LN1 stats + normalize/transpose
    ln_part_f32<<<dim3(8, 128), 256, 0, stream>>>(x, spart);
    ln1_norm_t<<<dim3(32, 128), 256, 0, stream>>>(x, n1g, n1b, spart, xn);
    // 2. merged KQ (stride-2) + V (stride-1) conv (XCD-swizzled)
    conv_kqv<<<dim3(10, 128), 512, 0, stream>>>(xn, wpk_kq, wpk_v, KQb, Vb, zpg);
    // 3. attention scores: p-split partials then combine+softmax
    attn_scores_part<<<dim3(8, 32), 256, 0, stream>>>(KQb, scpart);
    attn_soft<<<32, 256, 0, stream>>>(scpart, attbf);
    // 4. y = att @ v
    attn_apply_mfma<<<dim3(256, 4), 256, 0, stream>>>(attbf, Vb, Yb);
    // 5. Wo conv + bias + residual -> X1; fused LN2 partial stats (swizzled)
    conv_lds<32, 32, 32, 2, 8, true><<<dim3(8, 128), 512, 0, stream>>>(Yb, wpk_o, bo, x, X1, zpg, spart, 0, 0);
    // 6. LN2 normalize
    ln2_norm<<<dim3(64, 128), 256, 0, stream>>>(X1, g2t, b2t, spart, xn2);
    // 7-8. mixer: m1 NO swizzle (L3-fit input; swizzle cost -3.5us/WRITE+47MB
    //       at R13); m2 keeps swizzle (HBM-bound Hb stream, it helped)
    for (int s0 = 0; s0 < 128; s0 += chunk) {
        int n = (128 - s0 < chunk) ? (128 - s0) : chunk;
        conv_lds<32, 128, 64, 3, 8, false><<<dim3(16, n), 512, 0, stream>>>(xn2, wpk_m1, bm1, nullptr, Hb, zpg, nullptr, s0, 0);
        conv_lds<128, 32, 32, 4, 8, true><<<dim3(8, n), 512, 0, stream>>>(Hb, wpk_m2, bm2, X1, (float*)d_out, zpg, nullptr, 0, s0);
    }
}